// Round 1
// baseline (584.497 us; speedup 1.0000x reference)
//
#include <hip/hip_runtime.h>
#include <cstdint>

#define EPS 1e-5f
#define BB   8
#define CIN  384
#define HWs  4096
#define LT   32768
#define DD   128
#define NN   512
#define TOPK 81

// ---------------- K0: DR layernorm prep ----------------
// per row n: dr_ln (LN with norm2), drw = dr_ln*norm1_w, t2 = sum(norm1_b*dr_ln),
// rcr = 1/sqrt(sum dr_ln^2)
__global__ __launch_bounds__(64) void k_dr(const float* __restrict__ DR,
    const float* __restrict__ w2, const float* __restrict__ b2,
    const float* __restrict__ w1, const float* __restrict__ b1,
    float* __restrict__ drln, float* __restrict__ drw,
    float* __restrict__ t2, float* __restrict__ rcr) {
  int n = blockIdx.x;
  int lane = threadIdx.x;
  const float* row = DR + n * DD;
  float x0 = row[lane], x1 = row[lane + 64];
  float s = x0 + x1, sq = x0 * x0 + x1 * x1;
  #pragma unroll
  for (int o = 32; o; o >>= 1) { s += __shfl_xor(s, o); sq += __shfl_xor(sq, o); }
  float m = s * (1.f / 128.f);
  float v = sq * (1.f / 128.f) - m * m;
  float inv = rsqrtf(v + EPS);
  float y0 = (x0 - m) * inv * w2[lane] + b2[lane];
  float y1 = (x1 - m) * inv * w2[lane + 64] + b2[lane + 64];
  drln[n * DD + lane] = y0; drln[n * DD + lane + 64] = y1;
  float wa = w1[lane], wb = w1[lane + 64];
  drw[n * DD + lane] = y0 * wa; drw[n * DD + lane + 64] = y1 * wb;
  float pt2 = y0 * b1[lane] + y1 * b1[lane + 64];
  float pss = y0 * y0 + y1 * y1;
  #pragma unroll
  for (int o = 32; o; o >>= 1) { pt2 += __shfl_xor(pt2, o); pss += __shfl_xor(pss, o); }
  if (lane == 0) { t2[n] = pt2; rcr[n] = rsqrtf(pss); }
}

// ---------------- K1: conv_in (384 -> 128), x is [B,C,H,W] ----------------
// tile 64 l x 128 d, K-chunks of 32. thread: lg=t&15 (4 l), dg=t>>4 (8 d)
__global__ __launch_bounds__(256) void k_convin(const float* __restrict__ x,
    const float* __restrict__ Wm, const float* __restrict__ bias,
    float* __restrict__ xa) {
  __shared__ float xT[32][64];
  __shared__ float wT[32][132];
  int t = threadIdx.x;
  int l0 = blockIdx.x * 64;
  int b = l0 >> 12, hw0 = l0 & 4095;
  int lg = t & 15, dg = t >> 4;
  float acc[4][8];
  #pragma unroll
  for (int j = 0; j < 8; ++j) {
    float bb = bias[dg * 8 + j];
    #pragma unroll
    for (int i = 0; i < 4; ++i) acc[i][j] = bb;
  }
  const float* xb = x + (size_t)b * CIN * HWs + hw0;
  for (int c0 = 0; c0 < CIN; c0 += 32) {
    __syncthreads();
    #pragma unroll
    for (int idx = t; idx < 2048; idx += 256) {
      int cc = idx >> 6, ll = idx & 63;
      xT[cc][ll] = xb[(size_t)(c0 + cc) * HWs + ll];
    }
    #pragma unroll
    for (int idx = t; idx < 4096; idx += 256) {
      int dd = idx >> 5, cc = idx & 31;
      wT[cc][dd] = Wm[dd * CIN + c0 + cc];
    }
    __syncthreads();
    #pragma unroll
    for (int cc = 0; cc < 32; ++cc) {
      float4 a4 = *(const float4*)&xT[cc][lg * 4];
      float4 w0 = *(const float4*)&wT[cc][dg * 8];
      float4 w1v = *(const float4*)&wT[cc][dg * 8 + 4];
      float av[4] = {a4.x, a4.y, a4.z, a4.w};
      float wv[8] = {w0.x, w0.y, w0.z, w0.w, w1v.x, w1v.y, w1v.z, w1v.w};
      #pragma unroll
      for (int i = 0; i < 4; ++i)
        #pragma unroll
        for (int j = 0; j < 8; ++j)
          acc[i][j] = fmaf(av[i], wv[j], acc[i][j]);
    }
  }
  #pragma unroll
  for (int i = 0; i < 4; ++i) {
    float* dst = xa + (size_t)(l0 + lg * 4 + i) * DD + dg * 8;
    float4 o0 = {acc[i][0], acc[i][1], acc[i][2], acc[i][3]};
    float4 o1 = {acc[i][4], acc[i][5], acc[i][6], acc[i][7]};
    *(float4*)dst = o0; *(float4*)(dst + 4) = o1;
  }
}

// ---------------- K2: sem conv (128->128) + LN1 + 2nd-LN fold ----------------
// outputs A'[l,d] = (y - m2)*inv2*rcl   and  rcl[l]
__global__ __launch_bounds__(256) void k_sem(const float* __restrict__ A,
    const float* __restrict__ Wm, const float* __restrict__ bias,
    const float* __restrict__ w1, const float* __restrict__ b1,
    float* __restrict__ Ap, float* __restrict__ rclv) {
  __shared__ float xT[32][68];
  __shared__ float wT[32][132];
  __shared__ float raw[64][133];
  __shared__ float red1[64][4], red2[64][4];
  __shared__ float rowA[64], rowB[64];
  int t = threadIdx.x;
  int l0 = blockIdx.x * 64;
  int lg = t & 15, dg = t >> 4;
  float acc[4][8];
  #pragma unroll
  for (int j = 0; j < 8; ++j) {
    float bb = bias[dg * 8 + j];
    #pragma unroll
    for (int i = 0; i < 4; ++i) acc[i][j] = bb;
  }
  for (int c0 = 0; c0 < DD; c0 += 32) {
    __syncthreads();
    #pragma unroll
    for (int idx = t; idx < 2048; idx += 256) {
      int ll = idx >> 5, cc = idx & 31;
      xT[cc][ll] = A[(size_t)(l0 + ll) * DD + c0 + cc];
    }
    #pragma unroll
    for (int idx = t; idx < 4096; idx += 256) {
      int dd = idx >> 5, cc = idx & 31;
      wT[cc][dd] = Wm[dd * DD + c0 + cc];
    }
    __syncthreads();
    #pragma unroll
    for (int cc = 0; cc < 32; ++cc) {
      float4 a4 = *(const float4*)&xT[cc][lg * 4];
      float4 w0 = *(const float4*)&wT[cc][dg * 8];
      float4 w1v = *(const float4*)&wT[cc][dg * 8 + 4];
      float av[4] = {a4.x, a4.y, a4.z, a4.w};
      float wv[8] = {w0.x, w0.y, w0.z, w0.w, w1v.x, w1v.y, w1v.z, w1v.w};
      #pragma unroll
      for (int i = 0; i < 4; ++i)
        #pragma unroll
        for (int j = 0; j < 8; ++j)
          acc[i][j] = fmaf(av[i], wv[j], acc[i][j]);
    }
  }
  #pragma unroll
  for (int i = 0; i < 4; ++i)
    #pragma unroll
    for (int j = 0; j < 8; ++j)
      raw[lg * 4 + i][dg * 8 + j] = acc[i][j];
  __syncthreads();
  int r = t & 63, q = t >> 6;
  float ps = 0.f, pq = 0.f;
  #pragma unroll
  for (int j = 0; j < 32; ++j) { float vv = raw[r][q * 32 + j]; ps += vv; pq += vv * vv; }
  red1[r][q] = ps; red2[r][q] = pq;
  __syncthreads();
  if (t < 64) {
    float s = red1[t][0] + red1[t][1] + red1[t][2] + red1[t][3];
    float sq = red2[t][0] + red2[t][1] + red2[t][2] + red2[t][3];
    float m = s * (1.f / 128.f);
    float v = sq * (1.f / 128.f) - m * m;
    rowA[t] = m; rowB[t] = rsqrtf(v + EPS);
  }
  __syncthreads();
  float m = rowA[r], inv = rowB[r];
  ps = 0.f; pq = 0.f;
  #pragma unroll
  for (int j = 0; j < 32; ++j) {
    int d = q * 32 + j;
    float y = (raw[r][d] - m) * inv * w1[d] + b1[d];
    raw[r][d] = y;
    ps += y; pq += y * y;
  }
  __syncthreads();
  red1[r][q] = ps; red2[r][q] = pq;
  __syncthreads();
  if (t < 64) {
    float s2 = red1[t][0] + red1[t][1] + red1[t][2] + red1[t][3];
    float sq2 = red2[t][0] + red2[t][1] + red2[t][2] + red2[t][3];
    float m2 = s2 * (1.f / 128.f);
    float v2 = sq2 * (1.f / 128.f) - m2 * m2;
    float inv2 = rsqrtf(v2 + EPS);
    float rcl = rsqrtf(sq2);
    rowA[t] = m2; rowB[t] = inv2 * rcl;
    rclv[l0 + t] = rcl;
  }
  __syncthreads();
  for (int idx = t; idx < 8192; idx += 256) {
    int rr = idx >> 7, d = idx & 127;
    Ap[(size_t)l0 * DD + idx] = (raw[rr][d] - rowA[rr]) * rowB[rr];
  }
}

// ---------------- K3a: scores + softmax ----------------
// sim[l,n] = rcr[n]*(A'[l]·drw[n] + rcl[l]*t2[n]); p = softmax_n; maxv = 1/sumexp
__global__ __launch_bounds__(256) void k_scores(const float* __restrict__ Ap,
    const float* __restrict__ drw, const float* __restrict__ t2g,
    const float* __restrict__ rcrg, const float* __restrict__ rclg,
    float* __restrict__ p, float* __restrict__ maxv) {
  __shared__ float AT[128][34];
  __shared__ float dT[16][516];
  __shared__ float rcrL[512], t2L[512];
  __shared__ float red[32][17];
  int t = threadIdx.x;
  int l0 = blockIdx.x * 32;
  int lg = t & 15, ng = t >> 4;
  int n0 = ng * 32;
  for (int idx = t; idx < 4096; idx += 256) {
    int ll = idx >> 7, k = idx & 127;
    AT[k][ll] = Ap[(size_t)(l0 + ll) * DD + k];
  }
  for (int idx = t; idx < 512; idx += 256) { rcrL[idx] = rcrg[idx]; t2L[idx] = t2g[idx]; }
  float s0[32], s1[32];
  #pragma unroll
  for (int j = 0; j < 32; ++j) { s0[j] = 0.f; s1[j] = 0.f; }
  for (int kc = 0; kc < 8; ++kc) {
    __syncthreads();
    int k0 = kc * 16;
    for (int idx = t; idx < 8192; idx += 256) {
      int n = idx >> 4, kk = idx & 15;
      dT[kk][n] = drw[(size_t)n * DD + k0 + kk];
    }
    __syncthreads();
    #pragma unroll
    for (int kk = 0; kk < 16; ++kk) {
      float2 a2 = *(const float2*)&AT[k0 + kk][2 * lg];
      const float* wr = &dT[kk][n0];
      #pragma unroll
      for (int jj = 0; jj < 8; ++jj) {
        float4 w4 = *(const float4*)(wr + 4 * jj);
        s0[4 * jj + 0] = fmaf(a2.x, w4.x, s0[4 * jj + 0]);
        s0[4 * jj + 1] = fmaf(a2.x, w4.y, s0[4 * jj + 1]);
        s0[4 * jj + 2] = fmaf(a2.x, w4.z, s0[4 * jj + 2]);
        s0[4 * jj + 3] = fmaf(a2.x, w4.w, s0[4 * jj + 3]);
        s1[4 * jj + 0] = fmaf(a2.y, w4.x, s1[4 * jj + 0]);
        s1[4 * jj + 1] = fmaf(a2.y, w4.y, s1[4 * jj + 1]);
        s1[4 * jj + 2] = fmaf(a2.y, w4.z, s1[4 * jj + 2]);
        s1[4 * jj + 3] = fmaf(a2.y, w4.w, s1[4 * jj + 3]);
      }
    }
  }
  float rcl0 = rclg[l0 + 2 * lg], rcl1 = rclg[l0 + 2 * lg + 1];
  float m0 = -1e30f, m1 = -1e30f;
  #pragma unroll
  for (int j = 0; j < 32; ++j) {
    int n = n0 + j;
    s0[j] = rcrL[n] * (s0[j] + rcl0 * t2L[n]);
    s1[j] = rcrL[n] * (s1[j] + rcl1 * t2L[n]);
    m0 = fmaxf(m0, s0[j]); m1 = fmaxf(m1, s1[j]);
  }
  red[2 * lg][ng] = m0;
  red[2 * lg + 1][ng] = m1;
  __syncthreads();
  float M0 = -1e30f, M1 = -1e30f;
  #pragma unroll
  for (int j = 0; j < 16; ++j) { M0 = fmaxf(M0, red[2 * lg][j]); M1 = fmaxf(M1, red[2 * lg + 1][j]); }
  __syncthreads();
  float sum0 = 0.f, sum1 = 0.f;
  #pragma unroll
  for (int j = 0; j < 32; ++j) {
    s0[j] = expf(s0[j] - M0); sum0 += s0[j];
    s1[j] = expf(s1[j] - M1); sum1 += s1[j];
  }
  red[2 * lg][ng] = sum0; red[2 * lg + 1][ng] = sum1;
  __syncthreads();
  float S0 = 0.f, S1 = 0.f;
  #pragma unroll
  for (int j = 0; j < 16; ++j) { S0 += red[2 * lg][j]; S1 += red[2 * lg + 1][j]; }
  float rs0 = 1.f / S0, rs1 = 1.f / S1;
  if (ng == 0) { maxv[l0 + 2 * lg] = rs0; maxv[l0 + 2 * lg + 1] = rs1; }
  float* d0 = p + (size_t)(l0 + 2 * lg) * NN + n0;
  float* d1 = p + (size_t)(l0 + 2 * lg + 1) * NN + n0;
  #pragma unroll
  for (int jj = 0; jj < 8; ++jj) {
    float4 o0 = {s0[4 * jj] * rs0, s0[4 * jj + 1] * rs0, s0[4 * jj + 2] * rs0, s0[4 * jj + 3] * rs0};
    float4 o1 = {s1[4 * jj] * rs1, s1[4 * jj + 1] * rs1, s1[4 * jj + 2] * rs1, s1[4 * jj + 3] * rs1};
    *(float4*)(d0 + 4 * jj) = o0;
    *(float4*)(d1 + 4 * jj) = o1;
  }
}

// ---------------- K3b: degrad (p @ dr_ln) + conv_out (128->384) ----------------
__global__ __launch_bounds__(256) void k_deg(const float* __restrict__ p,
    const float* __restrict__ drln, const float* __restrict__ Wo,
    const float* __restrict__ bo, float* __restrict__ out_img) {
  __shared__ float degT[128][36];
  __shared__ float buf[12416];   // phaseC: pT[64*36] + drL[64*128] | phaseD: wT[32*388] | outS[32*388]
  float* pT = buf;
  float* drL = buf + 2304;
  int t = threadIdx.x;
  int l0 = blockIdx.x * 32;
  int lg = t & 7;
  int dg = t >> 3;               // 0..31
  float acc[4][4];
  #pragma unroll
  for (int i = 0; i < 4; ++i)
    #pragma unroll
    for (int j = 0; j < 4; ++j) acc[i][j] = 0.f;
  for (int nc = 0; nc < 8; ++nc) {
    int n0 = nc * 64;
    __syncthreads();
    for (int idx = t; idx < 2048; idx += 256) {
      int ll = idx >> 6, nn = idx & 63;
      pT[nn * 36 + ll] = p[(size_t)(l0 + ll) * NN + n0 + nn];
    }
    for (int idx = t; idx < 8192; idx += 256) {
      int nn = idx >> 7, k = idx & 127;
      drL[nn * 128 + k] = drln[(size_t)(n0 + nn) * DD + k];
    }
    __syncthreads();
    #pragma unroll
    for (int nn = 0; nn < 64; ++nn) {
      float4 a4 = *(const float4*)&pT[nn * 36 + 4 * lg];
      float4 w4 = *(const float4*)&drL[nn * 128 + 4 * dg];
      float av[4] = {a4.x, a4.y, a4.z, a4.w};
      float wv[4] = {w4.x, w4.y, w4.z, w4.w};
      #pragma unroll
      for (int i = 0; i < 4; ++i)
        #pragma unroll
        for (int j = 0; j < 4; ++j)
          acc[i][j] = fmaf(av[i], wv[j], acc[i][j]);
    }
  }
  __syncthreads();
  #pragma unroll
  for (int j = 0; j < 4; ++j) {
    float4 v = {acc[0][j], acc[1][j], acc[2][j], acc[3][j]};
    *(float4*)&degT[4 * dg + j][4 * lg] = v;
  }
  // phase D: out = deg @ Wo^T + bo
  int o0 = dg * 12;
  float acc2[4][12];
  #pragma unroll
  for (int j = 0; j < 12; ++j) {
    float bb = bo[o0 + j];
    #pragma unroll
    for (int i = 0; i < 4; ++i) acc2[i][j] = bb;
  }
  float* wT = buf;
  for (int kc = 0; kc < 4; ++kc) {
    __syncthreads();
    for (int idx = t; idx < 12288; idx += 256) {
      int o = idx >> 5, kk = idx & 31;
      wT[kk * 388 + o] = Wo[(size_t)o * DD + kc * 32 + kk];
    }
    __syncthreads();
    #pragma unroll
    for (int kk = 0; kk < 32; ++kk) {
      float4 a4 = *(const float4*)&degT[kc * 32 + kk][4 * lg];
      const float* wr = &wT[kk * 388 + o0];
      float4 w0 = *(const float4*)wr;
      float4 w1v = *(const float4*)(wr + 4);
      float4 w2v = *(const float4*)(wr + 8);
      float av[4] = {a4.x, a4.y, a4.z, a4.w};
      float wv[12] = {w0.x, w0.y, w0.z, w0.w, w1v.x, w1v.y, w1v.z, w1v.w,
                      w2v.x, w2v.y, w2v.z, w2v.w};
      #pragma unroll
      for (int i = 0; i < 4; ++i)
        #pragma unroll
        for (int j = 0; j < 12; ++j)
          acc2[i][j] = fmaf(av[i], wv[j], acc2[i][j]);
    }
  }
  __syncthreads();
  float* outS = buf;   // [32][388]
  #pragma unroll
  for (int i = 0; i < 4; ++i) {
    float4 q0 = {acc2[i][0], acc2[i][1], acc2[i][2], acc2[i][3]};
    float4 q1 = {acc2[i][4], acc2[i][5], acc2[i][6], acc2[i][7]};
    float4 q2 = {acc2[i][8], acc2[i][9], acc2[i][10], acc2[i][11]};
    float* dst = &outS[(4 * lg + i) * 388 + o0];
    *(float4*)dst = q0; *(float4*)(dst + 4) = q1; *(float4*)(dst + 8) = q2;
  }
  __syncthreads();
  int b = l0 >> 12, hw0 = l0 & 4095;
  float* ob = out_img + (size_t)b * CIN * HWs + hw0;
  for (int idx = t; idx < 12288; idx += 256) {
    int o = idx >> 5, ll = idx & 31;
    ob[(size_t)o * HWs + ll] = outS[ll * 388 + o];
  }
}

// ---------------- K4: mask (per-batch min-max of maxv^3) ----------------
__global__ __launch_bounds__(256) void k_mask(const float* __restrict__ maxv,
                                              float* __restrict__ outm) {
  int b = blockIdx.x, t = threadIdx.x;
  float c[16];
  float mn = 1e30f, mx = -1e30f;
  #pragma unroll
  for (int j = 0; j < 16; ++j) {
    float x = maxv[b * HWs + t + j * 256];
    float cc = x * x * x;
    c[j] = cc;
    mn = fminf(mn, cc); mx = fmaxf(mx, cc);
  }
  #pragma unroll
  for (int o = 32; o; o >>= 1) { mn = fminf(mn, __shfl_xor(mn, o)); mx = fmaxf(mx, __shfl_xor(mx, o)); }
  __shared__ float smn[4], smx[4];
  int w = t >> 6;
  if ((t & 63) == 0) { smn[w] = mn; smx[w] = mx; }
  __syncthreads();
  mn = fminf(fminf(smn[0], smn[1]), fminf(smn[2], smn[3]));
  mx = fmaxf(fmaxf(smx[0], smx[1]), fmaxf(smx[2], smx[3]));
  float sc = 1.f / (mx - mn);
  #pragma unroll
  for (int j = 0; j < 16; ++j)
    outm[b * HWs + t + j * 256] = 1.f - (c[j] - mn) * sc;
}

// ---------------- K5: top-81 per batch (desc value, ties -> lower index) --------
__global__ __launch_bounds__(256) void k_topk(const float* __restrict__ maxv,
                                              int* __restrict__ tix) {
  int b = blockIdx.x, t = threadIdx.x;
  unsigned long long key[16];
  #pragma unroll
  for (int j = 0; j < 16; ++j) {
    int idx = t + j * 256;
    unsigned int bits = __float_as_uint(maxv[b * HWs + idx]);  // maxv > 0 always
    key[j] = ((unsigned long long)bits << 32) | (unsigned int)(4095 - idx);
  }
  __shared__ unsigned long long wbest[4];
  for (int k = 0; k < TOPK; ++k) {
    unsigned long long best = 0ull;
    #pragma unroll
    for (int j = 0; j < 16; ++j) if (key[j] > best) best = key[j];
    #pragma unroll
    for (int o = 32; o; o >>= 1) {
      unsigned long long ot = __shfl_xor(best, o);
      if (ot > best) best = ot;
    }
    __syncthreads();                 // protect wbest from previous-iter readers
    if ((t & 63) == 0) wbest[t >> 6] = best;
    __syncthreads();
    unsigned long long B0 = wbest[0];
    if (wbest[1] > B0) B0 = wbest[1];
    if (wbest[2] > B0) B0 = wbest[2];
    if (wbest[3] > B0) B0 = wbest[3];
    int idx = 4095 - (int)(B0 & 0xFFFFFFFFull);
    if (t == 0) tix[b * TOPK + k] = idx;
    #pragma unroll
    for (int j = 0; j < 16; ++j) if ((t + j * 256) == idx) key[j] = 0ull;
  }
}

// ---------------- K6: gather results rows ----------------
__global__ __launch_bounds__(128) void k_gather(const float* __restrict__ p,
    const int* __restrict__ tix, float* __restrict__ outr) {
  int g = blockIdx.x;                 // (b*8 + b2)*81 + k
  int k = g % TOPK;
  int bb = g / TOPK;
  int b2 = bb & 7, b = bb >> 3;
  int idx = tix[b2 * TOPK + k];
  const float4* src = (const float4*)(p + ((size_t)b * HWs + idx) * NN);
  float4* dst = (float4*)(outr + (size_t)g * NN);
  dst[threadIdx.x] = src[threadIdx.x];
}

extern "C" void kernel_launch(void* const* d_in, const int* in_sizes, int n_in,
                              void* d_out, int out_size, void* d_ws, size_t ws_size,
                              hipStream_t stream) {
  const float* x    = (const float*)d_in[0];
  const float* DR   = (const float*)d_in[1];
  const float* win  = (const float*)d_in[2];
  const float* bin  = (const float*)d_in[3];
  const float* sw   = (const float*)d_in[4];
  const float* sb   = (const float*)d_in[5];
  const float* n1w  = (const float*)d_in[6];
  const float* n1b  = (const float*)d_in[7];
  const float* n2w  = (const float*)d_in[8];
  const float* n2b  = (const float*)d_in[9];
  const float* wout = (const float*)d_in[10];
  const float* bout = (const float*)d_in[11];
  float* out = (float*)d_out;
  float* W = (float*)d_ws;

  // workspace layout (floats)
  float* drln = W;                        // 65536
  float* drw  = W + 65536;                // 65536
  float* t2   = W + 131072;               // 512
  float* rcr  = W + 131584;               // 512
  float* rclv = W + 132096;               // 32768
  float* maxv = W + 164864;               // 32768
  float* Ap   = W + 197632;               // 4194304
  float* pbuf = W + 4391936;              // 16777216 (x_align aliases here)
  float* xa   = pbuf;
  int*   tix  = (int*)(W + 21169152);     // 648 ints
  // total ~84.7 MB

  float* out_mask = out;
  float* out_img  = out + 32768;
  float* out_res  = out + 32768 + 12582912;

  k_dr    <<<NN,   64,  0, stream>>>(DR, n2w, n2b, n1w, n1b, drln, drw, t2, rcr);
  k_convin<<<512,  256, 0, stream>>>(x, win, bin, xa);
  k_sem   <<<512,  256, 0, stream>>>(xa, sw, sb, n1w, n1b, Ap, rclv);
  k_scores<<<1024, 256, 0, stream>>>(Ap, drw, t2, rcr, rclv, pbuf, maxv);
  k_deg   <<<1024, 256, 0, stream>>>(pbuf, drln, wout, bout, out_img);
  k_mask  <<<BB,   256, 0, stream>>>(maxv, out_mask);
  k_topk  <<<BB,   256, 0, stream>>>(maxv, tix);
  k_gather<<<BB * BB * TOPK, 128, 0, stream>>>(pbuf, tix, out_res);
}

// Round 2
// 475.539 us; speedup vs baseline: 1.2291x; 1.2291x over previous
//
#include <hip/hip_runtime.h>
#include <cstdint>

#define EPS 1e-5f
#define BB   8
#define CIN  384
#define HWs  4096
#define LT   32768
#define DD   128
#define NN   512
#define TOPK 81

typedef short short8 __attribute__((ext_vector_type(8)));   // 8 bf16 (4 VGPRs) per guide §3
typedef float f32x4  __attribute__((ext_vector_type(4)));

__device__ __forceinline__ unsigned short f2bf(float x) {   // RNE, finite inputs
  unsigned u = __float_as_uint(x);
  u += 0x7fffu + ((u >> 16) & 1u);
  return (unsigned short)(u >> 16);
}
__device__ __forceinline__ float bf2f(unsigned short h) {
  return __uint_as_float(((unsigned)h) << 16);
}
// write element (row rc in tile, k) of an operand as hi/lo bf16 in MFMA frag order.
// frag layout (m89/m120-verified): lane=(k>>3&3)*16 + rc, j=k&7; frag=512 halfwords.
__device__ __forceinline__ void put_frag(unsigned short* buf, int tile, int rc, int k, float v) {
  int ks = k >> 5, g = (k >> 3) & 3, j = k & 7;
  int basehw = ((tile * 4 + ks) * 2) * 512 + (g * 16 + rc) * 8 + j;
  unsigned short hi = f2bf(v);
  buf[basehw] = hi;
  buf[basehw + 512] = f2bf(v - bf2f(hi));
}

// ---------------- K0: DR layernorm prep ----------------
// drln = LN2(DR); drwF = frag-swizzled hi/lo bf16 of drln*norm1_w;
// t2 = sum(norm1_b*drln); rcr = 1/||drln||
__global__ __launch_bounds__(64) void k_dr(const float* __restrict__ DR,
    const float* __restrict__ w2, const float* __restrict__ b2,
    const float* __restrict__ w1, const float* __restrict__ b1,
    float* __restrict__ drln, unsigned short* __restrict__ drwF,
    float* __restrict__ t2, float* __restrict__ rcr) {
  int n = blockIdx.x;
  int lane = threadIdx.x;
  const float* row = DR + n * DD;
  float x0 = row[lane], x1 = row[lane + 64];
  float s = x0 + x1, sq = x0 * x0 + x1 * x1;
  #pragma unroll
  for (int o = 32; o; o >>= 1) { s += __shfl_xor(s, o); sq += __shfl_xor(sq, o); }
  float m = s * (1.f / 128.f);
  float v = sq * (1.f / 128.f) - m * m;
  float inv = rsqrtf(v + EPS);
  float y0 = (x0 - m) * inv * w2[lane] + b2[lane];
  float y1 = (x1 - m) * inv * w2[lane + 64] + b2[lane + 64];
  drln[n * DD + lane] = y0; drln[n * DD + lane + 64] = y1;
  float wa = w1[lane], wb = w1[lane + 64];
  int nt = n >> 4, cc = n & 15;
  put_frag(drwF, nt, cc, lane, y0 * wa);
  put_frag(drwF, nt, cc, lane + 64, y1 * wb);
  float pt2 = y0 * b1[lane] + y1 * b1[lane + 64];
  float pss = y0 * y0 + y1 * y1;
  #pragma unroll
  for (int o = 32; o; o >>= 1) { pt2 += __shfl_xor(pt2, o); pss += __shfl_xor(pss, o); }
  if (lane == 0) { t2[n] = pt2; rcr[n] = rsqrtf(pss); }
}

// ---------------- K1: conv_in (384 -> 128), x is [B,C,H,W] ----------------
__global__ __launch_bounds__(256) void k_convin(const float* __restrict__ x,
    const float* __restrict__ Wm, const float* __restrict__ bias,
    float* __restrict__ xa) {
  __shared__ float xT[32][64];
  __shared__ float wT[32][132];
  int t = threadIdx.x;
  int l0 = blockIdx.x * 64;
  int b = l0 >> 12, hw0 = l0 & 4095;
  int lg = t & 15, dg = t >> 4;
  float acc[4][8];
  #pragma unroll
  for (int j = 0; j < 8; ++j) {
    float bb = bias[dg * 8 + j];
    #pragma unroll
    for (int i = 0; i < 4; ++i) acc[i][j] = bb;
  }
  const float* xb = x + (size_t)b * CIN * HWs + hw0;
  for (int c0 = 0; c0 < CIN; c0 += 32) {
    __syncthreads();
    #pragma unroll
    for (int idx = t; idx < 2048; idx += 256) {
      int cc = idx >> 6, ll = idx & 63;
      xT[cc][ll] = xb[(size_t)(c0 + cc) * HWs + ll];
    }
    #pragma unroll
    for (int idx = t; idx < 4096; idx += 256) {
      int dd = idx >> 5, cc = idx & 31;
      wT[cc][dd] = Wm[dd * CIN + c0 + cc];
    }
    __syncthreads();
    #pragma unroll
    for (int cc = 0; cc < 32; ++cc) {
      float4 a4 = *(const float4*)&xT[cc][lg * 4];
      float4 w0 = *(const float4*)&wT[cc][dg * 8];
      float4 w1v = *(const float4*)&wT[cc][dg * 8 + 4];
      float av[4] = {a4.x, a4.y, a4.z, a4.w};
      float wv[8] = {w0.x, w0.y, w0.z, w0.w, w1v.x, w1v.y, w1v.z, w1v.w};
      #pragma unroll
      for (int i = 0; i < 4; ++i)
        #pragma unroll
        for (int j = 0; j < 8; ++j)
          acc[i][j] = fmaf(av[i], wv[j], acc[i][j]);
    }
  }
  #pragma unroll
  for (int i = 0; i < 4; ++i) {
    float* dst = xa + (size_t)(l0 + lg * 4 + i) * DD + dg * 8;
    float4 o0 = {acc[i][0], acc[i][1], acc[i][2], acc[i][3]};
    float4 o1 = {acc[i][4], acc[i][5], acc[i][6], acc[i][7]};
    *(float4*)dst = o0; *(float4*)(dst + 4) = o1;
  }
}

// ---------------- K2: sem conv (128->128) + LN1 + 2nd-LN fold ----------------
// ApF = frag-swizzled hi/lo bf16 of A'[l,d] = (y-m2)*inv2*rcl; rclv[l]
__global__ __launch_bounds__(256) void k_sem(const float* __restrict__ A,
    const float* __restrict__ Wm, const float* __restrict__ bias,
    const float* __restrict__ w1, const float* __restrict__ b1,
    unsigned short* __restrict__ ApF, float* __restrict__ rclv) {
  __shared__ float xT[32][68];
  __shared__ float wT[32][132];
  __shared__ float raw[64][133];
  __shared__ float red1[64][4], red2[64][4];
  __shared__ float rowA[64], rowB[64];
  int t = threadIdx.x;
  int l0 = blockIdx.x * 64;
  int lg = t & 15, dg = t >> 4;
  float acc[4][8];
  #pragma unroll
  for (int j = 0; j < 8; ++j) {
    float bb = bias[dg * 8 + j];
    #pragma unroll
    for (int i = 0; i < 4; ++i) acc[i][j] = bb;
  }
  for (int c0 = 0; c0 < DD; c0 += 32) {
    __syncthreads();
    #pragma unroll
    for (int idx = t; idx < 2048; idx += 256) {
      int ll = idx >> 5, cc = idx & 31;
      xT[cc][ll] = A[(size_t)(l0 + ll) * DD + c0 + cc];
    }
    #pragma unroll
    for (int idx = t; idx < 4096; idx += 256) {
      int dd = idx >> 5, cc = idx & 31;
      wT[cc][dd] = Wm[dd * DD + c0 + cc];
    }
    __syncthreads();
    #pragma unroll
    for (int cc = 0; cc < 32; ++cc) {
      float4 a4 = *(const float4*)&xT[cc][lg * 4];
      float4 w0 = *(const float4*)&wT[cc][dg * 8];
      float4 w1v = *(const float4*)&wT[cc][dg * 8 + 4];
      float av[4] = {a4.x, a4.y, a4.z, a4.w};
      float wv[8] = {w0.x, w0.y, w0.z, w0.w, w1v.x, w1v.y, w1v.z, w1v.w};
      #pragma unroll
      for (int i = 0; i < 4; ++i)
        #pragma unroll
        for (int j = 0; j < 8; ++j)
          acc[i][j] = fmaf(av[i], wv[j], acc[i][j]);
    }
  }
  #pragma unroll
  for (int i = 0; i < 4; ++i)
    #pragma unroll
    for (int j = 0; j < 8; ++j)
      raw[lg * 4 + i][dg * 8 + j] = acc[i][j];
  __syncthreads();
  int r = t & 63, q = t >> 6;
  float ps = 0.f, pq = 0.f;
  #pragma unroll
  for (int j = 0; j < 32; ++j) { float vv = raw[r][q * 32 + j]; ps += vv; pq += vv * vv; }
  red1[r][q] = ps; red2[r][q] = pq;
  __syncthreads();
  if (t < 64) {
    float s = red1[t][0] + red1[t][1] + red1[t][2] + red1[t][3];
    float sq = red2[t][0] + red2[t][1] + red2[t][2] + red2[t][3];
    float m = s * (1.f / 128.f);
    float v = sq * (1.f / 128.f) - m * m;
    rowA[t] = m; rowB[t] = rsqrtf(v + EPS);
  }
  __syncthreads();
  float m = rowA[r], inv = rowB[r];
  ps = 0.f; pq = 0.f;
  #pragma unroll
  for (int j = 0; j < 32; ++j) {
    int d = q * 32 + j;
    float y = (raw[r][d] - m) * inv * w1[d] + b1[d];
    raw[r][d] = y;
    ps += y; pq += y * y;
  }
  __syncthreads();
  red1[r][q] = ps; red2[r][q] = pq;
  __syncthreads();
  if (t < 64) {
    float s2 = red1[t][0] + red1[t][1] + red1[t][2] + red1[t][3];
    float sq2 = red2[t][0] + red2[t][1] + red2[t][2] + red2[t][3];
    float m2 = s2 * (1.f / 128.f);
    float v2 = sq2 * (1.f / 128.f) - m2 * m2;
    float inv2 = rsqrtf(v2 + EPS);
    float rcl = rsqrtf(sq2);
    rowA[t] = m2; rowB[t] = inv2 * rcl;
    rclv[l0 + t] = rcl;
  }
  __syncthreads();
  for (int idx = t; idx < 8192; idx += 256) {
    int rr = idx >> 7, d = idx & 127;
    int l = l0 + rr;
    float v = (raw[rr][d] - rowA[rr]) * rowB[rr];
    put_frag(ApF, l >> 4, l & 15, d, v);
  }
}

// ---------------- K3a: scores + softmax (split-bf16 MFMA) ----------------
// sim[l,n] = rcr[n]*(A'[l]·drw[n] + rcl[l]*t2[n]); p = softmax_n; maxv = 1/sumexp
// block: 32 L-rows x all 512 N; wave w owns N-range [w*128, w*128+128)
__global__ __launch_bounds__(256) void k_scores(const unsigned short* __restrict__ ApF,
    const unsigned short* __restrict__ drwF, const float* __restrict__ t2g,
    const float* __restrict__ rcrg, const float* __restrict__ rclg,
    float* __restrict__ p, float* __restrict__ maxv) {
  __shared__ float sred[32][5];
  int t = threadIdx.x;
  int w = t >> 6, lane = t & 63, c = lane & 15, g = lane >> 4;
  int l0 = blockIdx.x * 32;
  int lt0 = blockIdx.x * 2;
  const short8* A8 = (const short8*)ApF;   // index unit = 8 halfwords; frag = 64 units
  const short8* B8 = (const short8*)drwF;
  f32x4 acc[2][8];
  #pragma unroll
  for (int il = 0; il < 2; ++il)
    #pragma unroll
    for (int jn = 0; jn < 8; ++jn) acc[il][jn] = (f32x4){0.f, 0.f, 0.f, 0.f};
  #pragma unroll
  for (int ks = 0; ks < 4; ++ks) {
    short8 ah0 = A8[((lt0 * 4 + ks) * 2 + 0) * 64 + lane];
    short8 al0 = A8[((lt0 * 4 + ks) * 2 + 1) * 64 + lane];
    short8 ah1 = A8[(((lt0 + 1) * 4 + ks) * 2 + 0) * 64 + lane];
    short8 al1 = A8[(((lt0 + 1) * 4 + ks) * 2 + 1) * 64 + lane];
    #pragma unroll
    for (int jn = 0; jn < 8; ++jn) {
      int nt = w * 8 + jn;
      short8 bh = B8[((nt * 4 + ks) * 2 + 0) * 64 + lane];
      short8 bl = B8[((nt * 4 + ks) * 2 + 1) * 64 + lane];
      acc[0][jn] = __builtin_amdgcn_mfma_f32_16x16x32_bf16(ah0, bh, acc[0][jn], 0, 0, 0);
      acc[0][jn] = __builtin_amdgcn_mfma_f32_16x16x32_bf16(ah0, bl, acc[0][jn], 0, 0, 0);
      acc[0][jn] = __builtin_amdgcn_mfma_f32_16x16x32_bf16(al0, bh, acc[0][jn], 0, 0, 0);
      acc[1][jn] = __builtin_amdgcn_mfma_f32_16x16x32_bf16(ah1, bh, acc[1][jn], 0, 0, 0);
      acc[1][jn] = __builtin_amdgcn_mfma_f32_16x16x32_bf16(ah1, bl, acc[1][jn], 0, 0, 0);
      acc[1][jn] = __builtin_amdgcn_mfma_f32_16x16x32_bf16(al1, bh, acc[1][jn], 0, 0, 0);
    }
  }
  // ---- epilogue: affine + softmax ----
  float rcrv[8], t2v[8];
  #pragma unroll
  for (int jn = 0; jn < 8; ++jn) {
    int n = w * 128 + jn * 16 + c;
    rcrv[jn] = rcrg[n]; t2v[jn] = t2g[n];
  }
  float rclr[2][4];
  #pragma unroll
  for (int il = 0; il < 2; ++il)
    #pragma unroll
    for (int r = 0; r < 4; ++r)
      rclr[il][r] = rclg[l0 + il * 16 + g * 4 + r];
  float M[2][4];
  #pragma unroll
  for (int il = 0; il < 2; ++il)
    #pragma unroll
    for (int r = 0; r < 4; ++r) M[il][r] = -1e30f;
  #pragma unroll
  for (int il = 0; il < 2; ++il)
    #pragma unroll
    for (int jn = 0; jn < 8; ++jn) {
      f32x4 a = acc[il][jn];
      #pragma unroll
      for (int r = 0; r < 4; ++r) {
        float s = rcrv[jn] * (a[r] + rclr[il][r] * t2v[jn]);
        a[r] = s;
        M[il][r] = fmaxf(M[il][r], s);
      }
      acc[il][jn] = a;
    }
  #pragma unroll
  for (int o = 1; o < 16; o <<= 1)
    #pragma unroll
    for (int il = 0; il < 2; ++il)
      #pragma unroll
      for (int r = 0; r < 4; ++r)
        M[il][r] = fmaxf(M[il][r], __shfl_xor(M[il][r], o));
  if (c == 0) {
    #pragma unroll
    for (int il = 0; il < 2; ++il)
      #pragma unroll
      for (int r = 0; r < 4; ++r)
        sred[il * 16 + g * 4 + r][w] = M[il][r];
  }
  __syncthreads();
  if (t < 32) {
    float mm = fmaxf(fmaxf(sred[t][0], sred[t][1]), fmaxf(sred[t][2], sred[t][3]));
    sred[t][4] = mm;
  }
  __syncthreads();
  float Mf[2][4];
  #pragma unroll
  for (int il = 0; il < 2; ++il)
    #pragma unroll
    for (int r = 0; r < 4; ++r)
      Mf[il][r] = sred[il * 16 + g * 4 + r][4];
  float S[2][4];
  #pragma unroll
  for (int il = 0; il < 2; ++il)
    #pragma unroll
    for (int r = 0; r < 4; ++r) S[il][r] = 0.f;
  #pragma unroll
  for (int il = 0; il < 2; ++il)
    #pragma unroll
    for (int jn = 0; jn < 8; ++jn) {
      f32x4 a = acc[il][jn];
      #pragma unroll
      for (int r = 0; r < 4; ++r) {
        float e = expf(a[r] - Mf[il][r]);
        a[r] = e;
        S[il][r] += e;
      }
      acc[il][jn] = a;
    }
  #pragma unroll
  for (int o = 1; o < 16; o <<= 1)
    #pragma unroll
    for (int il = 0; il < 2; ++il)
      #pragma unroll
      for (int r = 0; r < 4; ++r)
        S[il][r] += __shfl_xor(S[il][r], o);
  __syncthreads();
  if (c == 0) {
    #pragma unroll
    for (int il = 0; il < 2; ++il)
      #pragma unroll
      for (int r = 0; r < 4; ++r)
        sred[il * 16 + g * 4 + r][w] = S[il][r];
  }
  __syncthreads();
  if (t < 32) {
    float tot = sred[t][0] + sred[t][1] + sred[t][2] + sred[t][3];
    float rs = 1.f / tot;
    sred[t][4] = rs;
    maxv[l0 + t] = rs;
  }
  __syncthreads();
  #pragma unroll
  for (int il = 0; il < 2; ++il) {
    #pragma unroll
    for (int r = 0; r < 4; ++r) {
      int l = l0 + il * 16 + g * 4 + r;
      float rs = sred[il * 16 + g * 4 + r][4];
      float* pr = p + (size_t)l * NN + w * 128 + c;
      #pragma unroll
      for (int jn = 0; jn < 8; ++jn)
        pr[jn * 16] = acc[il][jn][r] * rs;
    }
  }
}

// ---------------- K3b: degrad (p @ dr_ln) + conv_out (128->384) ----------------
__global__ __launch_bounds__(256) void k_deg(const float* __restrict__ p,
    const float* __restrict__ drln, const float* __restrict__ Wo,
    const float* __restrict__ bo, float* __restrict__ out_img) {
  __shared__ float degT[128][36];
  __shared__ float buf[12416];
  float* pT = buf;
  float* drL = buf + 2304;
  int t = threadIdx.x;
  int l0 = blockIdx.x * 32;
  int lg = t & 7;
  int dg = t >> 3;
  float acc[4][4];
  #pragma unroll
  for (int i = 0; i < 4; ++i)
    #pragma unroll
    for (int j = 0; j < 4; ++j) acc[i][j] = 0.f;
  for (int nc = 0; nc < 8; ++nc) {
    int n0 = nc * 64;
    __syncthreads();
    for (int idx = t; idx < 2048; idx += 256) {
      int ll = idx >> 6, nn = idx & 63;
      pT[nn * 36 + ll] = p[(size_t)(l0 + ll) * NN + n0 + nn];
    }
    for (int idx = t; idx < 8192; idx += 256) {
      int nn = idx >> 7, k = idx & 127;
      drL[nn * 128 + k] = drln[(size_t)(n0 + nn) * DD + k];
    }
    __syncthreads();
    #pragma unroll
    for (int nn = 0; nn < 64; ++nn) {
      float4 a4 = *(const float4*)&pT[nn * 36 + 4 * lg];
      float4 w4 = *(const float4*)&drL[nn * 128 + 4 * dg];
      float av[4] = {a4.x, a4.y, a4.z, a4.w};
      float wv[4] = {w4.x, w4.y, w4.z, w4.w};
      #pragma unroll
      for (int i = 0; i < 4; ++i)
        #pragma unroll
        for (int j = 0; j < 4; ++j)
          acc[i][j] = fmaf(av[i], wv[j], acc[i][j]);
    }
  }
  __syncthreads();
  #pragma unroll
  for (int j = 0; j < 4; ++j) {
    float4 v = {acc[0][j], acc[1][j], acc[2][j], acc[3][j]};
    *(float4*)&degT[4 * dg + j][4 * lg] = v;
  }
  int o0 = dg * 12;
  float acc2[4][12];
  #pragma unroll
  for (int j = 0; j < 12; ++j) {
    float bb = bo[o0 + j];
    #pragma unroll
    for (int i = 0; i < 4; ++i) acc2[i][j] = bb;
  }
  float* wT = buf;
  for (int kc = 0; kc < 4; ++kc) {
    __syncthreads();
    for (int idx = t; idx < 12288; idx += 256) {
      int o = idx >> 5, kk = idx & 31;
      wT[kk * 388 + o] = Wo[(size_t)o * DD + kc * 32 + kk];
    }
    __syncthreads();
    #pragma unroll
    for (int kk = 0; kk < 32; ++kk) {
      float4 a4 = *(const float4*)&degT[kc * 32 + kk][4 * lg];
      const float* wr = &wT[kk * 388 + o0];
      float4 w0 = *(const float4*)wr;
      float4 w1v = *(const float4*)(wr + 4);
      float4 w2v = *(const float4*)(wr + 8);
      float av[4] = {a4.x, a4.y, a4.z, a4.w};
      float wv[12] = {w0.x, w0.y, w0.z, w0.w, w1v.x, w1v.y, w1v.z, w1v.w,
                      w2v.x, w2v.y, w2v.z, w2v.w};
      #pragma unroll
      for (int i = 0; i < 4; ++i)
        #pragma unroll
        for (int j = 0; j < 12; ++j)
          acc2[i][j] = fmaf(av[i], wv[j], acc2[i][j]);
    }
  }
  __syncthreads();
  float* outS = buf;
  #pragma unroll
  for (int i = 0; i < 4; ++i) {
    float4 q0 = {acc2[i][0], acc2[i][1], acc2[i][2], acc2[i][3]};
    float4 q1 = {acc2[i][4], acc2[i][5], acc2[i][6], acc2[i][7]};
    float4 q2 = {acc2[i][8], acc2[i][9], acc2[i][10], acc2[i][11]};
    float* dst = &outS[(4 * lg + i) * 388 + o0];
    *(float4*)dst = q0; *(float4*)(dst + 4) = q1; *(float4*)(dst + 8) = q2;
  }
  __syncthreads();
  int b = l0 >> 12, hw0 = l0 & 4095;
  float* ob = out_img + (size_t)b * CIN * HWs + hw0;
  for (int idx = t; idx < 12288; idx += 256) {
    int o = idx >> 5, ll = idx & 31;
    ob[(size_t)o * HWs + ll] = outS[ll * 388 + o];
  }
}

// ---------------- K4: mask (per-batch min-max of maxv^3) ----------------
__global__ __launch_bounds__(256) void k_mask(const float* __restrict__ maxv,
                                              float* __restrict__ outm) {
  int b = blockIdx.x, t = threadIdx.x;
  float c[16];
  float mn = 1e30f, mx = -1e30f;
  #pragma unroll
  for (int j = 0; j < 16; ++j) {
    float x = maxv[b * HWs + t + j * 256];
    float cc = x * x * x;
    c[j] = cc;
    mn = fminf(mn, cc); mx = fmaxf(mx, cc);
  }
  #pragma unroll
  for (int o = 32; o; o >>= 1) { mn = fminf(mn, __shfl_xor(mn, o)); mx = fmaxf(mx, __shfl_xor(mx, o)); }
  __shared__ float smn[4], smx[4];
  int w = t >> 6;
  if ((t & 63) == 0) { smn[w] = mn; smx[w] = mx; }
  __syncthreads();
  mn = fminf(fminf(smn[0], smn[1]), fminf(smn[2], smn[3]));
  mx = fmaxf(fmaxf(smx[0], smx[1]), fmaxf(smx[2], smx[3]));
  float sc = 1.f / (mx - mn);
  #pragma unroll
  for (int j = 0; j < 16; ++j)
    outm[b * HWs + t + j * 256] = 1.f - (c[j] - mn) * sc;
}

// ---------------- K5: top-81 per batch (desc value, ties -> lower index) --------
__global__ __launch_bounds__(256) void k_topk(const float* __restrict__ maxv,
                                              int* __restrict__ tix) {
  int b = blockIdx.x, t = threadIdx.x;
  unsigned long long key[16];
  #pragma unroll
  for (int j = 0; j < 16; ++j) {
    int idx = t + j * 256;
    unsigned int bits = __float_as_uint(maxv[b * HWs + idx]);
    key[j] = ((unsigned long long)bits << 32) | (unsigned int)(4095 - idx);
  }
  __shared__ unsigned long long wbest[4];
  for (int k = 0; k < TOPK; ++k) {
    unsigned long long best = 0ull;
    #pragma unroll
    for (int j = 0; j < 16; ++j) if (key[j] > best) best = key[j];
    #pragma unroll
    for (int o = 32; o; o >>= 1) {
      unsigned long long ot = __shfl_xor(best, o);
      if (ot > best) best = ot;
    }
    __syncthreads();
    if ((t & 63) == 0) wbest[t >> 6] = best;
    __syncthreads();
    unsigned long long B0 = wbest[0];
    if (wbest[1] > B0) B0 = wbest[1];
    if (wbest[2] > B0) B0 = wbest[2];
    if (wbest[3] > B0) B0 = wbest[3];
    int idx = 4095 - (int)(B0 & 0xFFFFFFFFull);
    if (t == 0) tix[b * TOPK + k] = idx;
    #pragma unroll
    for (int j = 0; j < 16; ++j) if ((t + j * 256) == idx) key[j] = 0ull;
  }
}

// ---------------- K6: gather results rows ----------------
__global__ __launch_bounds__(128) void k_gather(const float* __restrict__ p,
    const int* __restrict__ tix, float* __restrict__ outr) {
  int g = blockIdx.x;
  int k = g % TOPK;
  int bb = g / TOPK;
  int b2 = bb & 7, b = bb >> 3;
  int idx = tix[b2 * TOPK + k];
  const float4* src = (const float4*)(p + ((size_t)b * HWs + idx) * NN);
  float4* dst = (float4*)(outr + (size_t)g * NN);
  dst[threadIdx.x] = src[threadIdx.x];
}

extern "C" void kernel_launch(void* const* d_in, const int* in_sizes, int n_in,
                              void* d_out, int out_size, void* d_ws, size_t ws_size,
                              hipStream_t stream) {
  const float* x    = (const float*)d_in[0];
  const float* DR   = (const float*)d_in[1];
  const float* win  = (const float*)d_in[2];
  const float* bin  = (const float*)d_in[3];
  const float* sw   = (const float*)d_in[4];
  const float* sb   = (const float*)d_in[5];
  const float* n1w  = (const float*)d_in[6];
  const float* n1b  = (const float*)d_in[7];
  const float* n2w  = (const float*)d_in[8];
  const float* n2b  = (const float*)d_in[9];
  const float* wout = (const float*)d_in[10];
  const float* bout = (const float*)d_in[11];
  float* out = (float*)d_out;
  float* W = (float*)d_ws;

  // workspace layout (floats)
  float* drln = W;                              // 65536
  unsigned short* drwF = (unsigned short*)(W + 65536);   // 65536 floats = 131072 hw (512x128 hi+lo)
  float* t2   = W + 131072;                     // 512
  float* rcr  = W + 131584;                     // 512
  float* rclv = W + 132096;                     // 32768
  float* maxv = W + 164864;                     // 32768
  unsigned short* ApF = (unsigned short*)(W + 197632);   // 4194304 floats = 8388608 hw (32768x128 hi+lo)
  float* pbuf = W + 4391936;                    // 16777216 (x_align aliases here)
  float* xa   = pbuf;
  int*   tix  = (int*)(W + 21169152);           // 648 ints

  float* out_mask = out;
  float* out_img  = out + 32768;
  float* out_res  = out + 32768 + 12582912;

  k_dr    <<<NN,   64,  0, stream>>>(DR, n2w, n2b, n1w, n1b, drln, drwF, t2, rcr);
  k_convin<<<512,  256, 0, stream>>>(x, win, bin, xa);
  k_sem   <<<512,  256, 0, stream>>>(xa, sw, sb, n1w, n1b, ApF, rclv);
  k_scores<<<1024, 256, 0, stream>>>(ApF, drwF, t2, rcr, rclv, pbuf, maxv);
  k_deg   <<<1024, 256, 0, stream>>>(pbuf, drln, wout, bout, out_img);
  k_mask  <<<BB,   256, 0, stream>>>(maxv, out_mask);
  k_topk  <<<BB,   256, 0, stream>>>(maxv, tix);
  k_gather<<<BB * BB * TOPK, 128, 0, stream>>>(pbuf, tix, out_res);
}

// Round 3
// 358.190 us; speedup vs baseline: 1.6318x; 1.3276x over previous
//
#include <hip/hip_runtime.h>
#include <cstdint>

#define EPS 1e-5f
#define BB   8
#define CIN  384
#define HWs  4096
#define LT   32768
#define DD   128
#define NN   512
#define TOPK 81

typedef short short8 __attribute__((ext_vector_type(8)));   // 8 bf16 (4 VGPRs)
typedef float f32x4  __attribute__((ext_vector_type(4)));

__device__ __forceinline__ unsigned short f2bf(float x) {   // RNE, finite inputs
  unsigned u = __float_as_uint(x);
  u += 0x7fffu + ((u >> 16) & 1u);
  return (unsigned short)(u >> 16);
}
__device__ __forceinline__ float bf2f(unsigned u16) {
  return __uint_as_float(u16 << 16);
}
// write element (row rc in tile, k) of a B-operand as hi/lo bf16 in MFMA frag order.
// frag layout (verified R1): lane=((k>>3)&3)*16 + rc, j=k&7; frag=512 halfwords.
__device__ __forceinline__ void put_frag(unsigned short* buf, int tile, int rc, int k, float v) {
  int ks = k >> 5, g = (k >> 3) & 3, j = k & 7;
  int basehw = ((tile * 4 + ks) * 2) * 512 + (g * 16 + rc) * 8 + j;
  unsigned short hi = f2bf(v);
  buf[basehw] = hi;
  buf[basehw + 512] = f2bf(v - bf2f(hi));
}

// ---------------- K0: DR layernorm prep ----------------
// drwF = frag hi/lo bf16 of LN2(DR)*norm1_w (B-frags over n, K=d)
// drlnF = frag hi/lo bf16 of LN2(DR) (B-frags over d, K=n) for degrad GEMM
// t2 = sum(norm1_b*drln); rcr = 1/||drln||
__global__ __launch_bounds__(64) void k_dr(const float* __restrict__ DR,
    const float* __restrict__ w2, const float* __restrict__ b2,
    const float* __restrict__ w1, const float* __restrict__ b1,
    unsigned short* __restrict__ drwF, unsigned short* __restrict__ drlnF,
    float* __restrict__ t2, float* __restrict__ rcr) {
  int n = blockIdx.x;
  int lane = threadIdx.x;
  const float* row = DR + n * DD;
  float x0 = row[lane], x1 = row[lane + 64];
  float s = x0 + x1, sq = x0 * x0 + x1 * x1;
  #pragma unroll
  for (int o = 32; o; o >>= 1) { s += __shfl_xor(s, o); sq += __shfl_xor(sq, o); }
  float m = s * (1.f / 128.f);
  float v = sq * (1.f / 128.f) - m * m;
  float inv = rsqrtf(v + EPS);
  float y0 = (x0 - m) * inv * w2[lane] + b2[lane];
  float y1 = (x1 - m) * inv * w2[lane + 64] + b2[lane + 64];
  // drwF: B-frag col=n, k=d
  int nt = n >> 4, cc = n & 15;
  put_frag(drwF, nt, cc, lane, y0 * w1[lane]);
  put_frag(drwF, nt, cc, lane + 64, y1 * w1[lane + 64]);
  // drlnF: B-frag col=d, k=n
  int ks = n >> 5, gB = (n >> 3) & 3, j = n & 7;
  {
    int d = lane;
    unsigned short hi = f2bf(y0);
    int base = (((d >> 4) * 16 + ks) * 2) * 512 + (gB * 16 + (d & 15)) * 8 + j;
    drlnF[base] = hi;
    drlnF[base + 512] = f2bf(y0 - bf2f(hi));
  }
  {
    int d = lane + 64;
    unsigned short hi = f2bf(y1);
    int base = (((d >> 4) * 16 + ks) * 2) * 512 + (gB * 16 + (d & 15)) * 8 + j;
    drlnF[base] = hi;
    drlnF[base + 512] = f2bf(y1 - bf2f(hi));
  }
  float pt2 = y0 * b1[lane] + y1 * b1[lane + 64];
  float pss = y0 * y0 + y1 * y1;
  #pragma unroll
  for (int o = 32; o; o >>= 1) { pt2 += __shfl_xor(pt2, o); pss += __shfl_xor(pss, o); }
  if (lane == 0) { t2[n] = pt2; rcr[n] = rsqrtf(pss); }
}

// ---------------- K0b: Wo -> B-frag hi/lo (col=o, k=d) ----------------
__global__ __launch_bounds__(256) void k_wo(const float* __restrict__ Wo,
                                            unsigned short* __restrict__ WoF) {
  int ot = blockIdx.x;            // 0..23
  int t = threadIdx.x;
  int m = t >> 4;                 // o & 15
  int dblk = t & 15;              // 8-wide d block
  int o = ot * 16 + m;
  int ks2 = dblk >> 2, gB = dblk & 3;
  const float* src = Wo + (size_t)o * DD + dblk * 8;
  float4 f0 = *(const float4*)src;
  float4 f1 = *(const float4*)(src + 4);
  float vs[8] = {f0.x, f0.y, f0.z, f0.w, f1.x, f1.y, f1.z, f1.w};
  short8 hi, lo;
  #pragma unroll
  for (int j = 0; j < 8; ++j) {
    unsigned short h = f2bf(vs[j]);
    hi[j] = (short)h;
    lo[j] = (short)f2bf(vs[j] - bf2f(h));
  }
  short8* W8 = (short8*)WoF;
  int base8 = ((ot * 4 + ks2) * 2) * 64 + gB * 16 + m;
  W8[base8] = hi;
  W8[base8 + 64] = lo;
}

// ---------------- K1: conv_in (384 -> 128), x is [B,C,H,W] ----------------
__global__ __launch_bounds__(256) void k_convin(const float* __restrict__ x,
    const float* __restrict__ Wm, const float* __restrict__ bias,
    float* __restrict__ xa) {
  __shared__ float xT[32][64];
  __shared__ float wT[32][132];
  int t = threadIdx.x;
  int l0 = blockIdx.x * 64;
  int b = l0 >> 12, hw0 = l0 & 4095;
  int lg = t & 15, dg = t >> 4;
  float acc[4][8];
  #pragma unroll
  for (int j = 0; j < 8; ++j) {
    float bb = bias[dg * 8 + j];
    #pragma unroll
    for (int i = 0; i < 4; ++i) acc[i][j] = bb;
  }
  const float* xb = x + (size_t)b * CIN * HWs + hw0;
  for (int c0 = 0; c0 < CIN; c0 += 32) {
    __syncthreads();
    #pragma unroll
    for (int idx = t; idx < 2048; idx += 256) {
      int cc = idx >> 6, ll = idx & 63;
      xT[cc][ll] = xb[(size_t)(c0 + cc) * HWs + ll];
    }
    #pragma unroll
    for (int idx = t; idx < 4096; idx += 256) {
      int dd = idx >> 5, cc = idx & 31;
      wT[cc][dd] = Wm[dd * CIN + c0 + cc];
    }
    __syncthreads();
    #pragma unroll
    for (int cc = 0; cc < 32; ++cc) {
      float4 a4 = *(const float4*)&xT[cc][lg * 4];
      float4 w0 = *(const float4*)&wT[cc][dg * 8];
      float4 w1v = *(const float4*)&wT[cc][dg * 8 + 4];
      float av[4] = {a4.x, a4.y, a4.z, a4.w};
      float wv[8] = {w0.x, w0.y, w0.z, w0.w, w1v.x, w1v.y, w1v.z, w1v.w};
      #pragma unroll
      for (int i = 0; i < 4; ++i)
        #pragma unroll
        for (int j = 0; j < 8; ++j)
          acc[i][j] = fmaf(av[i], wv[j], acc[i][j]);
    }
  }
  #pragma unroll
  for (int i = 0; i < 4; ++i) {
    float* dst = xa + (size_t)(l0 + lg * 4 + i) * DD + dg * 8;
    float4 o0 = {acc[i][0], acc[i][1], acc[i][2], acc[i][3]};
    float4 o1 = {acc[i][4], acc[i][5], acc[i][6], acc[i][7]};
    *(float4*)dst = o0; *(float4*)(dst + 4) = o1;
  }
}

// ---------------- K2: sem conv (128->128) + LN1 + 2nd-LN fold ----------------
__global__ __launch_bounds__(256) void k_sem(const float* __restrict__ A,
    const float* __restrict__ Wm, const float* __restrict__ bias,
    const float* __restrict__ w1, const float* __restrict__ b1,
    unsigned short* __restrict__ ApF, float* __restrict__ rclv) {
  __shared__ float xT[32][68];
  __shared__ float wT[32][132];
  __shared__ float raw[64][133];
  __shared__ float red1[64][4], red2[64][4];
  __shared__ float rowA[64], rowB[64];
  int t = threadIdx.x;
  int l0 = blockIdx.x * 64;
  int lg = t & 15, dg = t >> 4;
  float acc[4][8];
  #pragma unroll
  for (int j = 0; j < 8; ++j) {
    float bb = bias[dg * 8 + j];
    #pragma unroll
    for (int i = 0; i < 4; ++i) acc[i][j] = bb;
  }
  for (int c0 = 0; c0 < DD; c0 += 32) {
    __syncthreads();
    #pragma unroll
    for (int idx = t; idx < 2048; idx += 256) {
      int ll = idx >> 5, cc = idx & 31;
      xT[cc][ll] = A[(size_t)(l0 + ll) * DD + c0 + cc];
    }
    #pragma unroll
    for (int idx = t; idx < 4096; idx += 256) {
      int dd = idx >> 5, cc = idx & 31;
      wT[cc][dd] = Wm[dd * DD + c0 + cc];
    }
    __syncthreads();
    #pragma unroll
    for (int cc = 0; cc < 32; ++cc) {
      float4 a4 = *(const float4*)&xT[cc][lg * 4];
      float4 w0 = *(const float4*)&wT[cc][dg * 8];
      float4 w1v = *(const float4*)&wT[cc][dg * 8 + 4];
      float av[4] = {a4.x, a4.y, a4.z, a4.w};
      float wv[8] = {w0.x, w0.y, w0.z, w0.w, w1v.x, w1v.y, w1v.z, w1v.w};
      #pragma unroll
      for (int i = 0; i < 4; ++i)
        #pragma unroll
        for (int j = 0; j < 8; ++j)
          acc[i][j] = fmaf(av[i], wv[j], acc[i][j]);
    }
  }
  #pragma unroll
  for (int i = 0; i < 4; ++i)
    #pragma unroll
    for (int j = 0; j < 8; ++j)
      raw[lg * 4 + i][dg * 8 + j] = acc[i][j];
  __syncthreads();
  int r = t & 63, q = t >> 6;
  float ps = 0.f, pq = 0.f;
  #pragma unroll
  for (int j = 0; j < 32; ++j) { float vv = raw[r][q * 32 + j]; ps += vv; pq += vv * vv; }
  red1[r][q] = ps; red2[r][q] = pq;
  __syncthreads();
  if (t < 64) {
    float s = red1[t][0] + red1[t][1] + red1[t][2] + red1[t][3];
    float sq = red2[t][0] + red2[t][1] + red2[t][2] + red2[t][3];
    float m = s * (1.f / 128.f);
    float v = sq * (1.f / 128.f) - m * m;
    rowA[t] = m; rowB[t] = rsqrtf(v + EPS);
  }
  __syncthreads();
  float m = rowA[r], inv = rowB[r];
  ps = 0.f; pq = 0.f;
  #pragma unroll
  for (int j = 0; j < 32; ++j) {
    int d = q * 32 + j;
    float y = (raw[r][d] - m) * inv * w1[d] + b1[d];
    raw[r][d] = y;
    ps += y; pq += y * y;
  }
  __syncthreads();
  red1[r][q] = ps; red2[r][q] = pq;
  __syncthreads();
  if (t < 64) {
    float s2 = red1[t][0] + red1[t][1] + red1[t][2] + red1[t][3];
    float sq2 = red2[t][0] + red2[t][1] + red2[t][2] + red2[t][3];
    float m2 = s2 * (1.f / 128.f);
    float v2 = sq2 * (1.f / 128.f) - m2 * m2;
    float inv2 = rsqrtf(v2 + EPS);
    float rcl = rsqrtf(sq2);
    rowA[t] = m2; rowB[t] = inv2 * rcl;
    rclv[l0 + t] = rcl;
  }
  __syncthreads();
  for (int idx = t; idx < 8192; idx += 256) {
    int rr = idx >> 7, d = idx & 127;
    int l = l0 + rr;
    float v = (raw[rr][d] - rowA[rr]) * rowB[rr];
    // ApF is A-operand frag: row=l, k=d — same index algebra as put_frag
    put_frag(ApF, l >> 4, l & 15, d, v);
  }
}

// ---------------- K3a: scores + softmax (split-bf16 MFMA) ----------------
// sim[l,n] = rcr[n]*(A'[l]·drw[n] + rcl[l]*t2[n]); p = softmax_n -> pF (bf16 A-frags);
// maxv = 1/sumexp
__global__ __launch_bounds__(256) void k_scores(const unsigned short* __restrict__ ApF,
    const unsigned short* __restrict__ drwF, const float* __restrict__ t2g,
    const float* __restrict__ rcrg, const float* __restrict__ rclg,
    unsigned short* __restrict__ pF, float* __restrict__ maxv) {
  __shared__ float sred[32][5];
  int t = threadIdx.x;
  int w = t >> 6, lane = t & 63, c = lane & 15, g = lane >> 4;
  int l0 = blockIdx.x * 32;
  int lt0 = blockIdx.x * 2;
  const short8* A8 = (const short8*)ApF;
  const short8* B8 = (const short8*)drwF;
  f32x4 acc[2][8];
  #pragma unroll
  for (int il = 0; il < 2; ++il)
    #pragma unroll
    for (int jn = 0; jn < 8; ++jn) acc[il][jn] = (f32x4){0.f, 0.f, 0.f, 0.f};
  #pragma unroll
  for (int ks = 0; ks < 4; ++ks) {
    short8 ah0 = A8[((lt0 * 4 + ks) * 2 + 0) * 64 + lane];
    short8 al0 = A8[((lt0 * 4 + ks) * 2 + 1) * 64 + lane];
    short8 ah1 = A8[(((lt0 + 1) * 4 + ks) * 2 + 0) * 64 + lane];
    short8 al1 = A8[(((lt0 + 1) * 4 + ks) * 2 + 1) * 64 + lane];
    #pragma unroll
    for (int jn = 0; jn < 8; ++jn) {
      int nt = w * 8 + jn;
      short8 bh = B8[((nt * 4 + ks) * 2 + 0) * 64 + lane];
      short8 bl = B8[((nt * 4 + ks) * 2 + 1) * 64 + lane];
      acc[0][jn] = __builtin_amdgcn_mfma_f32_16x16x32_bf16(ah0, bh, acc[0][jn], 0, 0, 0);
      acc[0][jn] = __builtin_amdgcn_mfma_f32_16x16x32_bf16(ah0, bl, acc[0][jn], 0, 0, 0);
      acc[0][jn] = __builtin_amdgcn_mfma_f32_16x16x32_bf16(al0, bh, acc[0][jn], 0, 0, 0);
      acc[1][jn] = __builtin_amdgcn_mfma_f32_16x16x32_bf16(ah1, bh, acc[1][jn], 0, 0, 0);
      acc[1][jn] = __builtin_amdgcn_mfma_f32_16x16x32_bf16(ah1, bl, acc[1][jn], 0, 0, 0);
      acc[1][jn] = __builtin_amdgcn_mfma_f32_16x16x32_bf16(al1, bh, acc[1][jn], 0, 0, 0);
    }
  }
  // ---- epilogue: affine + softmax ----
  float rcrv[8], t2v[8];
  #pragma unroll
  for (int jn = 0; jn < 8; ++jn) {
    int n = w * 128 + jn * 16 + c;
    rcrv[jn] = rcrg[n]; t2v[jn] = t2g[n];
  }
  float rclr[2][4];
  #pragma unroll
  for (int il = 0; il < 2; ++il)
    #pragma unroll
    for (int r = 0; r < 4; ++r)
      rclr[il][r] = rclg[l0 + il * 16 + g * 4 + r];
  float M[2][4];
  #pragma unroll
  for (int il = 0; il < 2; ++il)
    #pragma unroll
    for (int r = 0; r < 4; ++r) M[il][r] = -1e30f;
  #pragma unroll
  for (int il = 0; il < 2; ++il)
    #pragma unroll
    for (int jn = 0; jn < 8; ++jn) {
      f32x4 a = acc[il][jn];
      #pragma unroll
      for (int r = 0; r < 4; ++r) {
        float s = rcrv[jn] * (a[r] + rclr[il][r] * t2v[jn]);
        a[r] = s;
        M[il][r] = fmaxf(M[il][r], s);
      }
      acc[il][jn] = a;
    }
  #pragma unroll
  for (int o = 1; o < 16; o <<= 1)
    #pragma unroll
    for (int il = 0; il < 2; ++il)
      #pragma unroll
      for (int r = 0; r < 4; ++r)
        M[il][r] = fmaxf(M[il][r], __shfl_xor(M[il][r], o));
  if (c == 0) {
    #pragma unroll
    for (int il = 0; il < 2; ++il)
      #pragma unroll
      for (int r = 0; r < 4; ++r)
        sred[il * 16 + g * 4 + r][w] = M[il][r];
  }
  __syncthreads();
  if (t < 32) {
    float mm = fmaxf(fmaxf(sred[t][0], sred[t][1]), fmaxf(sred[t][2], sred[t][3]));
    sred[t][4] = mm;
  }
  __syncthreads();
  float Mf[2][4];
  #pragma unroll
  for (int il = 0; il < 2; ++il)
    #pragma unroll
    for (int r = 0; r < 4; ++r)
      Mf[il][r] = sred[il * 16 + g * 4 + r][4];
  float S[2][4];
  #pragma unroll
  for (int il = 0; il < 2; ++il)
    #pragma unroll
    for (int r = 0; r < 4; ++r) S[il][r] = 0.f;
  #pragma unroll
  for (int il = 0; il < 2; ++il)
    #pragma unroll
    for (int jn = 0; jn < 8; ++jn) {
      f32x4 a = acc[il][jn];
      #pragma unroll
      for (int r = 0; r < 4; ++r) {
        float e = expf(a[r] - Mf[il][r]);
        a[r] = e;
        S[il][r] += e;
      }
      acc[il][jn] = a;
    }
  #pragma unroll
  for (int o = 1; o < 16; o <<= 1)
    #pragma unroll
    for (int il = 0; il < 2; ++il)
      #pragma unroll
      for (int r = 0; r < 4; ++r)
        S[il][r] += __shfl_xor(S[il][r], o);
  __syncthreads();
  if (c == 0) {
    #pragma unroll
    for (int il = 0; il < 2; ++il)
      #pragma unroll
      for (int r = 0; r < 4; ++r)
        sred[il * 16 + g * 4 + r][w] = S[il][r];
  }
  __syncthreads();
  if (t < 32) {
    float tot = sred[t][0] + sred[t][1] + sred[t][2] + sred[t][3];
    float rs = 1.f / tot;
    sred[t][4] = rs;
    maxv[l0 + t] = rs;
  }
  __syncthreads();
  // write p as bf16 in A-frag order (row=l, k=n)
  #pragma unroll
  for (int il = 0; il < 2; ++il) {
    int lt = lt0 + il;
    #pragma unroll
    for (int r = 0; r < 4; ++r) {
      int mrow = g * 4 + r;
      float rs = sred[il * 16 + mrow][4];
      #pragma unroll
      for (int jn = 0; jn < 8; ++jn) {
        int ks = w * 4 + (jn >> 1);
        int gB = (jn * 2 + (c >> 3)) & 3;
        pF[((lt * 16 + ks) * 64 + gB * 16 + mrow) * 8 + (c & 7)] =
            f2bf(acc[il][jn][r] * rs);
      }
    }
  }
}

// ---------------- K3b: degrad (pF @ drlnF) + conv_out (128->384), all MFMA ----------------
__global__ __launch_bounds__(256) void k_deg(const unsigned short* __restrict__ pF,
    const unsigned short* __restrict__ drlnF, const unsigned short* __restrict__ WoF,
    const float* __restrict__ bo, float* __restrict__ out_img) {
  __shared__ float smem[64 * 132];   // phase1/2: degS [64][132]; epilogue: outS [64 l][65]
  int t = threadIdx.x;
  int w = t >> 6, lane = t & 63, c = lane & 15, g = lane >> 4;
  int l0 = blockIdx.x * 64;
  int lt0 = l0 >> 4;
  const short8* P8 = (const short8*)pF;
  const short8* D8 = (const short8*)drlnF;
  const short8* W8 = (const short8*)WoF;
  // ---- phase 1: deg[64][128] = p @ drln (K=512); wave w owns d-tiles {2w, 2w+1}
  f32x4 acc[4][2];
  #pragma unroll
  for (int lt = 0; lt < 4; ++lt)
    #pragma unroll
    for (int j2 = 0; j2 < 2; ++j2) acc[lt][j2] = (f32x4){0.f, 0.f, 0.f, 0.f};
  for (int ks = 0; ks < 16; ++ks) {
    short8 a0 = P8[((lt0 + 0) * 16 + ks) * 64 + lane];
    short8 a1 = P8[((lt0 + 1) * 16 + ks) * 64 + lane];
    short8 a2 = P8[((lt0 + 2) * 16 + ks) * 64 + lane];
    short8 a3 = P8[((lt0 + 3) * 16 + ks) * 64 + lane];
    #pragma unroll
    for (int j2 = 0; j2 < 2; ++j2) {
      int dt = w * 2 + j2;
      short8 bh = D8[((dt * 16 + ks) * 2 + 0) * 64 + lane];
      short8 bl = D8[((dt * 16 + ks) * 2 + 1) * 64 + lane];
      acc[0][j2] = __builtin_amdgcn_mfma_f32_16x16x32_bf16(a0, bh, acc[0][j2], 0, 0, 0);
      acc[0][j2] = __builtin_amdgcn_mfma_f32_16x16x32_bf16(a0, bl, acc[0][j2], 0, 0, 0);
      acc[1][j2] = __builtin_amdgcn_mfma_f32_16x16x32_bf16(a1, bh, acc[1][j2], 0, 0, 0);
      acc[1][j2] = __builtin_amdgcn_mfma_f32_16x16x32_bf16(a1, bl, acc[1][j2], 0, 0, 0);
      acc[2][j2] = __builtin_amdgcn_mfma_f32_16x16x32_bf16(a2, bh, acc[2][j2], 0, 0, 0);
      acc[2][j2] = __builtin_amdgcn_mfma_f32_16x16x32_bf16(a2, bl, acc[2][j2], 0, 0, 0);
      acc[3][j2] = __builtin_amdgcn_mfma_f32_16x16x32_bf16(a3, bh, acc[3][j2], 0, 0, 0);
      acc[3][j2] = __builtin_amdgcn_mfma_f32_16x16x32_bf16(a3, bl, acc[3][j2], 0, 0, 0);
    }
  }
  // deg -> LDS fp32 (C-layout scatter; 2-way banks = free)
  #pragma unroll
  for (int lt = 0; lt < 4; ++lt)
    #pragma unroll
    for (int j2 = 0; j2 < 2; ++j2)
      #pragma unroll
      for (int r = 0; r < 4; ++r)
        smem[(lt * 16 + g * 4 + r) * 132 + w * 32 + j2 * 16 + c] = acc[lt][j2][r];
  __syncthreads();
  // ---- phase 2: out[64][384] = deg @ Wo^T (K=128); wave w owns o-tiles w*6..w*6+5
  f32x4 acc2[4][6];
  #pragma unroll
  for (int lt = 0; lt < 4; ++lt)
    #pragma unroll
    for (int ot = 0; ot < 6; ++ot) acc2[lt][ot] = (f32x4){0.f, 0.f, 0.f, 0.f};
  #pragma unroll
  for (int ks2 = 0; ks2 < 4; ++ks2) {
    short8 dh[4];
    #pragma unroll
    for (int lt = 0; lt < 4; ++lt) {
      const float* src = &smem[(lt * 16 + c) * 132 + ks2 * 32 + g * 8];
      float4 f0 = *(const float4*)src;
      float4 f1 = *(const float4*)(src + 4);
      float vs[8] = {f0.x, f0.y, f0.z, f0.w, f1.x, f1.y, f1.z, f1.w};
      #pragma unroll
      for (int j = 0; j < 8; ++j) dh[lt][j] = (short)f2bf(vs[j]);
    }
    #pragma unroll
    for (int ot = 0; ot < 6; ++ot) {
      int otg = w * 6 + ot;
      short8 wh = W8[((otg * 4 + ks2) * 2 + 0) * 64 + lane];
      short8 wl = W8[((otg * 4 + ks2) * 2 + 1) * 64 + lane];
      #pragma unroll
      for (int lt = 0; lt < 4; ++lt) {
        acc2[lt][ot] = __builtin_amdgcn_mfma_f32_16x16x32_bf16(dh[lt], wh, acc2[lt][ot], 0, 0, 0);
        acc2[lt][ot] = __builtin_amdgcn_mfma_f32_16x16x32_bf16(dh[lt], wl, acc2[lt][ot], 0, 0, 0);
      }
    }
  }
  __syncthreads();   // degS dead; reuse as outS
  // ---- epilogue: bias + LDS transpose + coalesced store
  int b = l0 >> 12, hw0 = l0 & 4095;
  float* ob = out_img + (size_t)b * CIN * HWs + hw0;
  float bov[6];
  #pragma unroll
  for (int ot = 0; ot < 6; ++ot) bov[ot] = bo[w * 96 + ot * 16 + c];
  for (int ot = 0; ot < 6; ++ot) {
    #pragma unroll
    for (int lt = 0; lt < 4; ++lt)
      #pragma unroll
      for (int r = 0; r < 4; ++r)
        smem[(lt * 16 + g * 4 + r) * 65 + w * 16 + c] = acc2[lt][ot][r] + bov[ot];
    __syncthreads();
    #pragma unroll
    for (int i = 0; i < 16; ++i) {
      int idx = t + i * 256;              // 64 o x 64 l
      int o_l = idx >> 6, ll = idx & 63;
      int o = (o_l >> 4) * 96 + ot * 16 + (o_l & 15);
      ob[(size_t)o * HWs + ll] = smem[ll * 65 + o_l];
    }
    __syncthreads();
  }
}

// ---------------- K4: mask (per-batch min-max of maxv^3) ----------------
__global__ __launch_bounds__(256) void k_mask(const float* __restrict__ maxv,
                                              float* __restrict__ outm) {
  int b = blockIdx.x, t = threadIdx.x;
  float c[16];
  float mn = 1e30f, mx = -1e30f;
  #pragma unroll
  for (int j = 0; j < 16; ++j) {
    float x = maxv[b * HWs + t + j * 256];
    float cc = x * x * x;
    c[j] = cc;
    mn = fminf(mn, cc); mx = fmaxf(mx, cc);
  }
  #pragma unroll
  for (int o = 32; o; o >>= 1) { mn = fminf(mn, __shfl_xor(mn, o)); mx = fmaxf(mx, __shfl_xor(mx, o)); }
  __shared__ float smn[4], smx[4];
  int w = t >> 6;
  if ((t & 63) == 0) { smn[w] = mn; smx[w] = mx; }
  __syncthreads();
  mn = fminf(fminf(smn[0], smn[1]), fminf(smn[2], smn[3]));
  mx = fmaxf(fmaxf(smx[0], smx[1]), fmaxf(smx[2], smx[3]));
  float sc = 1.f / (mx - mn);
  #pragma unroll
  for (int j = 0; j < 16; ++j)
    outm[b * HWs + t + j * 256] = 1.f - (c[j] - mn) * sc;
}

// ---------------- K5: top-81 per batch (desc value, ties -> lower index) --------
__global__ __launch_bounds__(256) void k_topk(const float* __restrict__ maxv,
                                              int* __restrict__ tix) {
  int b = blockIdx.x, t = threadIdx.x;
  unsigned long long key[16];
  #pragma unroll
  for (int j = 0; j < 16; ++j) {
    int idx = t + j * 256;
    unsigned int bits = __float_as_uint(maxv[b * HWs + idx]);
    key[j] = ((unsigned long long)bits << 32) | (unsigned int)(4095 - idx);
  }
  __shared__ unsigned long long wbest[4];
  for (int k = 0; k < TOPK; ++k) {
    unsigned long long best = 0ull;
    #pragma unroll
    for (int j = 0; j < 16; ++j) if (key[j] > best) best = key[j];
    #pragma unroll
    for (int o = 32; o; o >>= 1) {
      unsigned long long ot = __shfl_xor(best, o);
      if (ot > best) best = ot;
    }
    __syncthreads();
    if ((t & 63) == 0) wbest[t >> 6] = best;
    __syncthreads();
    unsigned long long B0 = wbest[0];
    if (wbest[1] > B0) B0 = wbest[1];
    if (wbest[2] > B0) B0 = wbest[2];
    if (wbest[3] > B0) B0 = wbest[3];
    int idx = 4095 - (int)(B0 & 0xFFFFFFFFull);
    if (t == 0) tix[b * TOPK + k] = idx;
    #pragma unroll
    for (int j = 0; j < 16; ++j) if ((t + j * 256) == idx) key[j] = 0ull;
  }
}

// ---------------- K6: gather results rows from pF (bf16 frags -> fp32) --------
__global__ __launch_bounds__(128) void k_gather(const unsigned short* __restrict__ pF,
    const int* __restrict__ tix, float* __restrict__ outr) {
  int gB_ = blockIdx.x;
  int k = gB_ % TOPK;
  int bb = gB_ / TOPK;
  int b2 = bb & 7, b = bb >> 3;
  int l = b * HWs + tix[b2 * TOPK + k];
  int lt = l >> 4, mrow = l & 15;
  int t = threadIdx.x;            // n0 = 4*t
  int ks = t >> 3, gq = (t >> 1) & 3, j0 = (t & 1) * 4;
  int base = ((lt * 16 + ks) * 64 + gq * 16 + mrow) * 8 + j0;
  const unsigned* src = (const unsigned*)(pF + base);
  unsigned u0 = src[0], u1 = src[1];
  float4 v = {bf2f(u0 & 0xffffu), bf2f(u0 >> 16), bf2f(u1 & 0xffffu), bf2f(u1 >> 16)};
  *(float4*)(outr + (size_t)gB_ * NN + t * 4) = v;
}

extern "C" void kernel_launch(void* const* d_in, const int* in_sizes, int n_in,
                              void* d_out, int out_size, void* d_ws, size_t ws_size,
                              hipStream_t stream) {
  const float* x    = (const float*)d_in[0];
  const float* DR   = (const float*)d_in[1];
  const float* win  = (const float*)d_in[2];
  const float* bin  = (const float*)d_in[3];
  const float* sw   = (const float*)d_in[4];
  const float* sb   = (const float*)d_in[5];
  const float* n1w  = (const float*)d_in[6];
  const float* n1b  = (const float*)d_in[7];
  const float* n2w  = (const float*)d_in[8];
  const float* n2b  = (const float*)d_in[9];
  const float* wout = (const float*)d_in[10];
  const float* bout = (const float*)d_in[11];
  float* out = (float*)d_out;
  float* W = (float*)d_ws;

  // workspace layout (float offsets)
  unsigned short* drwF  = (unsigned short*)(W);            // 131072 hw = 65536 f
  float* t2   = W + 65536;                                 // 512
  float* rcr  = W + 66048;                                 // 512
  float* rclv = W + 66560;                                 // 32768
  float* maxv = W + 99328;                                 // 32768
  unsigned short* drlnF = (unsigned short*)(W + 132096);   // 131072 hw = 65536 f
  unsigned short* WoF   = (unsigned short*)(W + 197632);   // 98304 hw = 49152 f
  unsigned short* ApF   = (unsigned short*)(W + 246784);   // 8388608 hw = 4194304 f
  float* xa   = W + 4441088;                               // 16777216 f (dead after k_sem)
  unsigned short* pF = (unsigned short*)(W + 4441088);     // 16777216 hw (aliases xa)
  int*   tix  = (int*)(W + 21218304);                      // 648 ints
  // total ~84.9 MB

  float* out_mask = out;
  float* out_img  = out + 32768;
  float* out_res  = out + 32768 + 12582912;

  k_dr    <<<NN,   64,  0, stream>>>(DR, n2w, n2b, n1w, n1b, drwF, drlnF, t2, rcr);
  k_wo    <<<24,   256, 0, stream>>>(wout, WoF);
  k_convin<<<512,  256, 0, stream>>>(x, win, bin, xa);
  k_sem   <<<512,  256, 0, stream>>>(xa, sw, sb, n1w, n1b, ApF, rclv);
  k_scores<<<1024, 256, 0, stream>>>(ApF, drwF, t2, rcr, rclv, pF, maxv);
  k_deg   <<<512,  256, 0, stream>>>(pF, drlnF, WoF, bout, out_img);
  k_mask  <<<BB,   256, 0, stream>>>(maxv, out_mask);
  k_topk  <<<BB,   256, 0, stream>>>(maxv, tix);
  k_gather<<<BB * BB * TOPK, 128, 0, stream>>>(pF, tix, out_res);
}

// Round 4
// 293.239 us; speedup vs baseline: 1.9932x; 1.2215x over previous
//
#include <hip/hip_runtime.h>
#include <cstdint>

#define EPS 1e-5f
#define BB   8
#define CIN  384
#define HWs  4096
#define LT   32768
#define DD   128
#define NN   512
#define TOPK 81

typedef short short8 __attribute__((ext_vector_type(8)));   // 8 bf16 (4 VGPRs)
typedef float f32x4  __attribute__((ext_vector_type(4)));

__device__ __forceinline__ unsigned short f2bf(float x) {   // RNE, finite inputs
  unsigned u = __float_as_uint(x);
  u += 0x7fffu + ((u >> 16) & 1u);
  return (unsigned short)(u >> 16);
}
__device__ __forceinline__ float bf2f(unsigned u16) {
  return __uint_as_float(u16 << 16);
}
// write element (row rc in tile, k) of an operand as hi/lo bf16 in MFMA frag order.
// frag layout (HW-verified R1-R3): lane=((k>>3)&3)*16 + rc, j=k&7.
__device__ __forceinline__ void put_frag(unsigned short* buf, int tile, int rc, int k, float v) {
  int ks = k >> 5, g = (k >> 3) & 3, j = k & 7;
  int basehw = ((tile * 4 + ks) * 2) * 512 + (g * 16 + rc) * 8 + j;
  unsigned short hi = f2bf(v);
  buf[basehw] = hi;
  buf[basehw + 512] = f2bf(v - bf2f(hi));
}

// ---------------- K0: DR layernorm prep ----------------
__global__ __launch_bounds__(64) void k_dr(const float* __restrict__ DR,
    const float* __restrict__ w2, const float* __restrict__ b2,
    const float* __restrict__ w1, const float* __restrict__ b1,
    unsigned short* __restrict__ drwF, unsigned short* __restrict__ drlnF,
    float* __restrict__ t2, float* __restrict__ rcr) {
  int n = blockIdx.x;
  int lane = threadIdx.x;
  const float* row = DR + n * DD;
  float x0 = row[lane], x1 = row[lane + 64];
  float s = x0 + x1, sq = x0 * x0 + x1 * x1;
  #pragma unroll
  for (int o = 32; o; o >>= 1) { s += __shfl_xor(s, o); sq += __shfl_xor(sq, o); }
  float m = s * (1.f / 128.f);
  float v = sq * (1.f / 128.f) - m * m;
  float inv = rsqrtf(v + EPS);
  float y0 = (x0 - m) * inv * w2[lane] + b2[lane];
  float y1 = (x1 - m) * inv * w2[lane + 64] + b2[lane + 64];
  // drwF: B-frag col=n, k=d (nkt=4)
  int nt = n >> 4, cc = n & 15;
  put_frag(drwF, nt, cc, lane, y0 * w1[lane]);
  put_frag(drwF, nt, cc, lane + 64, y1 * w1[lane + 64]);
  // drlnF: B-frag col=d, k=n (nkt=16)
  int ks = n >> 5, gB = (n >> 3) & 3, j = n & 7;
  {
    int d = lane;
    unsigned short hi = f2bf(y0);
    int base = (((d >> 4) * 16 + ks) * 2) * 512 + (gB * 16 + (d & 15)) * 8 + j;
    drlnF[base] = hi;
    drlnF[base + 512] = f2bf(y0 - bf2f(hi));
  }
  {
    int d = lane + 64;
    unsigned short hi = f2bf(y1);
    int base = (((d >> 4) * 16 + ks) * 2) * 512 + (gB * 16 + (d & 15)) * 8 + j;
    drlnF[base] = hi;
    drlnF[base + 512] = f2bf(y1 - bf2f(hi));
  }
  float pt2 = y0 * b1[lane] + y1 * b1[lane + 64];
  float pss = y0 * y0 + y1 * y1;
  #pragma unroll
  for (int o = 32; o; o >>= 1) { pt2 += __shfl_xor(pt2, o); pss += __shfl_xor(pss, o); }
  if (lane == 0) { t2[n] = pt2; rcr[n] = rsqrtf(pss); }
}

// ---------------- K0b: generic [R,K] row-major -> B-frag hi/lo (col=r, k) --------
// grid (R/16, K/128); 256 threads: m=t>>4 (row in tile), kg=t&15 (8-wide k group)
__global__ __launch_bounds__(256) void k_bprep(const float* __restrict__ src,
                                               unsigned short* __restrict__ dst,
                                               int K) {
  int rt = blockIdx.x, kb = blockIdx.y;
  int t = threadIdx.x, m = t >> 4, kg = t & 15;
  int k0 = kb * 128 + kg * 8;
  const float* s = src + (size_t)(rt * 16 + m) * K + k0;
  float4 f0 = *(const float4*)s;
  float4 f1 = *(const float4*)(s + 4);
  float vs[8] = {f0.x, f0.y, f0.z, f0.w, f1.x, f1.y, f1.z, f1.w};
  short8 hi, lo;
  #pragma unroll
  for (int j = 0; j < 8; ++j) {
    unsigned short h = f2bf(vs[j]);
    hi[j] = (short)h;
    lo[j] = (short)f2bf(vs[j] - bf2f(h));
  }
  int nkt = K >> 5;
  int ks = k0 >> 5, g = (k0 >> 3) & 3;
  short8* D8 = (short8*)dst;
  int base = ((rt * nkt + ks) * 2) * 64 + g * 16 + m;
  D8[base] = hi;
  D8[base + 64] = lo;
}

// ---------------- K1: conv_in (384 -> 128), split-bf16 MFMA ----------------
// A-frags loaded straight from x [B,C,HW] (16-lane/64B coalesced); B = WinF (L2).
// Epilogue: +bias, LDS roundtrip, pack xaF (A-frags hi/lo, nkt=4) for k_sem.
__global__ __launch_bounds__(256) void k_convin(const float* __restrict__ x,
    const unsigned short* __restrict__ WinF, const float* __restrict__ bias,
    unsigned short* __restrict__ xaF) {
  __shared__ float smem[64 * 132];
  int t = threadIdx.x;
  int w = t >> 6, lane = t & 63, m = lane & 15, g = lane >> 4;
  int l0 = blockIdx.x * 64;
  int b = l0 >> 12, hw0 = l0 & 4095;
  const float* xb = x + (size_t)b * CIN * HWs + hw0;
  const short8* B8 = (const short8*)WinF;
  f32x4 acc[4][2];
  #pragma unroll
  for (int lt = 0; lt < 4; ++lt)
    #pragma unroll
    for (int j2 = 0; j2 < 2; ++j2) acc[lt][j2] = (f32x4){0.f, 0.f, 0.f, 0.f};
  for (int ks = 0; ks < 12; ++ks) {
    short8 ah[4], al[4];
    const float* xc = xb + (size_t)(ks * 32 + g * 8) * HWs;
    #pragma unroll
    for (int lt = 0; lt < 4; ++lt) {
      const float* xcl = xc + lt * 16 + m;
      float v[8];
      #pragma unroll
      for (int j = 0; j < 8; ++j) v[j] = xcl[(size_t)j * HWs];
      #pragma unroll
      for (int j = 0; j < 8; ++j) {
        unsigned short h = f2bf(v[j]);
        ah[lt][j] = (short)h;
        al[lt][j] = (short)f2bf(v[j] - bf2f(h));
      }
    }
    #pragma unroll
    for (int j2 = 0; j2 < 2; ++j2) {
      int dt = w * 2 + j2;
      short8 bh = B8[((dt * 12 + ks) * 2 + 0) * 64 + lane];
      short8 bl = B8[((dt * 12 + ks) * 2 + 1) * 64 + lane];
      #pragma unroll
      for (int lt = 0; lt < 4; ++lt) {
        acc[lt][j2] = __builtin_amdgcn_mfma_f32_16x16x32_bf16(ah[lt], bh, acc[lt][j2], 0, 0, 0);
        acc[lt][j2] = __builtin_amdgcn_mfma_f32_16x16x32_bf16(ah[lt], bl, acc[lt][j2], 0, 0, 0);
        acc[lt][j2] = __builtin_amdgcn_mfma_f32_16x16x32_bf16(al[lt], bh, acc[lt][j2], 0, 0, 0);
      }
    }
  }
  float bia[2] = {bias[w * 32 + m], bias[w * 32 + 16 + m]};
  #pragma unroll
  for (int lt = 0; lt < 4; ++lt)
    #pragma unroll
    for (int j2 = 0; j2 < 2; ++j2)
      #pragma unroll
      for (int r = 0; r < 4; ++r)
        smem[(lt * 16 + g * 4 + r) * 132 + (w * 2 + j2) * 16 + m] = acc[lt][j2][r] + bia[j2];
  __syncthreads();
  short8* X8 = (short8*)xaF;
  #pragma unroll
  for (int it = 0; it < 4; ++it) {
    int idx = it * 256 + t;
    int l = idx & 63, dq = idx >> 6;
    const float* src = &smem[l * 132 + dq * 8];
    float4 f0 = *(const float4*)src;
    float4 f1 = *(const float4*)(src + 4);
    float vs[8] = {f0.x, f0.y, f0.z, f0.w, f1.x, f1.y, f1.z, f1.w};
    short8 hi, lo;
    #pragma unroll
    for (int j = 0; j < 8; ++j) {
      unsigned short h = f2bf(vs[j]);
      hi[j] = (short)h;
      lo[j] = (short)f2bf(vs[j] - bf2f(h));
    }
    int ltg = (l0 + l) >> 4;
    int idx8 = ((ltg * 4 + (dq >> 2)) * 2) * 64 + (dq & 3) * 16 + (l & 15);
    X8[idx8] = hi;
    X8[idx8 + 64] = lo;
  }
}

// ---------------- K2: sem conv (128->128) MFMA + LN1 + 2nd-LN fold ----------------
__global__ __launch_bounds__(256) void k_sem(const unsigned short* __restrict__ xaF,
    const unsigned short* __restrict__ semWF, const float* __restrict__ bias,
    const float* __restrict__ w1, const float* __restrict__ b1,
    unsigned short* __restrict__ ApF, float* __restrict__ rclv) {
  __shared__ float smem[64 * 132];
  __shared__ float sredS[64][4], sredQ[64][4];
  __shared__ float rowM[64], rowI[64];
  int t = threadIdx.x;
  int w = t >> 6, lane = t & 63, m = lane & 15, g = lane >> 4;
  int l0 = blockIdx.x * 64;
  int lt0 = l0 >> 4;
  const short8* A8 = (const short8*)xaF;
  const short8* B8 = (const short8*)semWF;
  f32x4 acc[4][2];
  #pragma unroll
  for (int lt = 0; lt < 4; ++lt)
    #pragma unroll
    for (int j2 = 0; j2 < 2; ++j2) acc[lt][j2] = (f32x4){0.f, 0.f, 0.f, 0.f};
  #pragma unroll
  for (int ks = 0; ks < 4; ++ks) {
    short8 ah[4], al[4];
    #pragma unroll
    for (int lt = 0; lt < 4; ++lt) {
      ah[lt] = A8[(((lt0 + lt) * 4 + ks) * 2 + 0) * 64 + lane];
      al[lt] = A8[(((lt0 + lt) * 4 + ks) * 2 + 1) * 64 + lane];
    }
    #pragma unroll
    for (int j2 = 0; j2 < 2; ++j2) {
      int dt = w * 2 + j2;
      short8 bh = B8[((dt * 4 + ks) * 2 + 0) * 64 + lane];
      short8 bl = B8[((dt * 4 + ks) * 2 + 1) * 64 + lane];
      #pragma unroll
      for (int lt = 0; lt < 4; ++lt) {
        acc[lt][j2] = __builtin_amdgcn_mfma_f32_16x16x32_bf16(ah[lt], bh, acc[lt][j2], 0, 0, 0);
        acc[lt][j2] = __builtin_amdgcn_mfma_f32_16x16x32_bf16(ah[lt], bl, acc[lt][j2], 0, 0, 0);
        acc[lt][j2] = __builtin_amdgcn_mfma_f32_16x16x32_bf16(al[lt], bh, acc[lt][j2], 0, 0, 0);
      }
    }
  }
  // bias
  float bia[2] = {bias[w * 32 + m], bias[w * 32 + 16 + m]};
  #pragma unroll
  for (int lt = 0; lt < 4; ++lt)
    #pragma unroll
    for (int j2 = 0; j2 < 2; ++j2)
      #pragma unroll
      for (int r = 0; r < 4; ++r) acc[lt][j2][r] += bia[j2];
  // ---- LN pass 1 stats (reduce over d: 2 own cols + 16 c-lanes + 4 waves)
  float s1[4][4], q1[4][4];
  #pragma unroll
  for (int lt = 0; lt < 4; ++lt)
    #pragma unroll
    for (int r = 0; r < 4; ++r) {
      float a = acc[lt][0][r], b2v = acc[lt][1][r];
      s1[lt][r] = a + b2v;
      q1[lt][r] = a * a + b2v * b2v;
    }
  #pragma unroll
  for (int o = 1; o < 16; o <<= 1)
    #pragma unroll
    for (int lt = 0; lt < 4; ++lt)
      #pragma unroll
      for (int r = 0; r < 4; ++r) {
        s1[lt][r] += __shfl_xor(s1[lt][r], o);
        q1[lt][r] += __shfl_xor(q1[lt][r], o);
      }
  if (m == 0) {
    #pragma unroll
    for (int lt = 0; lt < 4; ++lt)
      #pragma unroll
      for (int r = 0; r < 4; ++r) {
        sredS[lt * 16 + g * 4 + r][w] = s1[lt][r];
        sredQ[lt * 16 + g * 4 + r][w] = q1[lt][r];
      }
  }
  __syncthreads();
  if (t < 64) {
    float S = sredS[t][0] + sredS[t][1] + sredS[t][2] + sredS[t][3];
    float Q = sredQ[t][0] + sredQ[t][1] + sredQ[t][2] + sredQ[t][3];
    float mu = S * (1.f / 128.f);
    float var = Q * (1.f / 128.f) - mu * mu;
    rowM[t] = mu;
    rowI[t] = rsqrtf(var + EPS);
  }
  __syncthreads();
  // ---- y = LN1(raw); stats pass 2
  float w1v[2] = {w1[w * 32 + m], w1[w * 32 + 16 + m]};
  float b1v[2] = {b1[w * 32 + m], b1[w * 32 + 16 + m]};
  #pragma unroll
  for (int lt = 0; lt < 4; ++lt)
    #pragma unroll
    for (int r = 0; r < 4; ++r) {
      float mu = rowM[lt * 16 + g * 4 + r];
      float iv = rowI[lt * 16 + g * 4 + r];
      float y0 = (acc[lt][0][r] - mu) * iv * w1v[0] + b1v[0];
      float y1 = (acc[lt][1][r] - mu) * iv * w1v[1] + b1v[1];
      acc[lt][0][r] = y0; acc[lt][1][r] = y1;
      s1[lt][r] = y0 + y1;
      q1[lt][r] = y0 * y0 + y1 * y1;
    }
  #pragma unroll
  for (int o = 1; o < 16; o <<= 1)
    #pragma unroll
    for (int lt = 0; lt < 4; ++lt)
      #pragma unroll
      for (int r = 0; r < 4; ++r) {
        s1[lt][r] += __shfl_xor(s1[lt][r], o);
        q1[lt][r] += __shfl_xor(q1[lt][r], o);
      }
  if (m == 0) {
    #pragma unroll
    for (int lt = 0; lt < 4; ++lt)
      #pragma unroll
      for (int r = 0; r < 4; ++r) {
        sredS[lt * 16 + g * 4 + r][w] = s1[lt][r];
        sredQ[lt * 16 + g * 4 + r][w] = q1[lt][r];
      }
  }
  __syncthreads();
  if (t < 64) {
    float S = sredS[t][0] + sredS[t][1] + sredS[t][2] + sredS[t][3];
    float Q = sredQ[t][0] + sredQ[t][1] + sredQ[t][2] + sredQ[t][3];
    float m2 = S * (1.f / 128.f);
    float v2 = Q * (1.f / 128.f) - m2 * m2;
    float inv2 = rsqrtf(v2 + EPS);
    float rcl = rsqrtf(Q);
    rowM[t] = m2;
    rowI[t] = inv2 * rcl;
    rclv[l0 + t] = rcl;
  }
  __syncthreads();
  // ---- A' = (y - m2)*inv2*rcl -> smem
  #pragma unroll
  for (int lt = 0; lt < 4; ++lt)
    #pragma unroll
    for (int r = 0; r < 4; ++r) {
      float m2 = rowM[lt * 16 + g * 4 + r];
      float sc = rowI[lt * 16 + g * 4 + r];
      smem[(lt * 16 + g * 4 + r) * 132 + w * 32 + m] = (acc[lt][0][r] - m2) * sc;
      smem[(lt * 16 + g * 4 + r) * 132 + w * 32 + 16 + m] = (acc[lt][1][r] - m2) * sc;
    }
  __syncthreads();
  // ---- frag-pack ApF (nkt=4)
  short8* O8 = (short8*)ApF;
  #pragma unroll
  for (int it = 0; it < 4; ++it) {
    int idx = it * 256 + t;
    int l = idx & 63, dq = idx >> 6;
    const float* src = &smem[l * 132 + dq * 8];
    float4 f0 = *(const float4*)src;
    float4 f1 = *(const float4*)(src + 4);
    float vs[8] = {f0.x, f0.y, f0.z, f0.w, f1.x, f1.y, f1.z, f1.w};
    short8 hi, lo;
    #pragma unroll
    for (int j = 0; j < 8; ++j) {
      unsigned short h = f2bf(vs[j]);
      hi[j] = (short)h;
      lo[j] = (short)f2bf(vs[j] - bf2f(h));
    }
    int ltg = (l0 + l) >> 4;
    int idx8 = ((ltg * 4 + (dq >> 2)) * 2) * 64 + (dq & 3) * 16 + (l & 15);
    O8[idx8] = hi;
    O8[idx8 + 64] = lo;
  }
}

// ---------------- K3a: scores + softmax (split-bf16 MFMA) ----------------
__global__ __launch_bounds__(256) void k_scores(const unsigned short* __restrict__ ApF,
    const unsigned short* __restrict__ drwF, const float* __restrict__ t2g,
    const float* __restrict__ rcrg, const float* __restrict__ rclg,
    unsigned short* __restrict__ pF, float* __restrict__ maxv) {
  __shared__ float sred[32][5];
  int t = threadIdx.x;
  int w = t >> 6, lane = t & 63, c = lane & 15, g = lane >> 4;
  int l0 = blockIdx.x * 32;
  int lt0 = blockIdx.x * 2;
  const short8* A8 = (const short8*)ApF;
  const short8* B8 = (const short8*)drwF;
  f32x4 acc[2][8];
  #pragma unroll
  for (int il = 0; il < 2; ++il)
    #pragma unroll
    for (int jn = 0; jn < 8; ++jn) acc[il][jn] = (f32x4){0.f, 0.f, 0.f, 0.f};
  #pragma unroll
  for (int ks = 0; ks < 4; ++ks) {
    short8 ah0 = A8[((lt0 * 4 + ks) * 2 + 0) * 64 + lane];
    short8 al0 = A8[((lt0 * 4 + ks) * 2 + 1) * 64 + lane];
    short8 ah1 = A8[(((lt0 + 1) * 4 + ks) * 2 + 0) * 64 + lane];
    short8 al1 = A8[(((lt0 + 1) * 4 + ks) * 2 + 1) * 64 + lane];
    #pragma unroll
    for (int jn = 0; jn < 8; ++jn) {
      int nt = w * 8 + jn;
      short8 bh = B8[((nt * 4 + ks) * 2 + 0) * 64 + lane];
      short8 bl = B8[((nt * 4 + ks) * 2 + 1) * 64 + lane];
      acc[0][jn] = __builtin_amdgcn_mfma_f32_16x16x32_bf16(ah0, bh, acc[0][jn], 0, 0, 0);
      acc[0][jn] = __builtin_amdgcn_mfma_f32_16x16x32_bf16(ah0, bl, acc[0][jn], 0, 0, 0);
      acc[0][jn] = __builtin_amdgcn_mfma_f32_16x16x32_bf16(al0, bh, acc[0][jn], 0, 0, 0);
      acc[1][jn] = __builtin_amdgcn_mfma_f32_16x16x32_bf16(ah1, bh, acc[1][jn], 0, 0, 0);
      acc[1][jn] = __builtin_amdgcn_mfma_f32_16x16x32_bf16(ah1, bl, acc[1][jn], 0, 0, 0);
      acc[1][jn] = __builtin_amdgcn_mfma_f32_16x16x32_bf16(al1, bh, acc[1][jn], 0, 0, 0);
    }
  }
  float rcrv[8], t2v[8];
  #pragma unroll
  for (int jn = 0; jn < 8; ++jn) {
    int n = w * 128 + jn * 16 + c;
    rcrv[jn] = rcrg[n]; t2v[jn] = t2g[n];
  }
  float rclr[2][4];
  #pragma unroll
  for (int il = 0; il < 2; ++il)
    #pragma unroll
    for (int r = 0; r < 4; ++r)
      rclr[il][r] = rclg[l0 + il * 16 + g * 4 + r];
  float M[2][4];
  #pragma unroll
  for (int il = 0; il < 2; ++il)
    #pragma unroll
    for (int r = 0; r < 4; ++r) M[il][r] = -1e30f;
  #pragma unroll
  for (int il = 0; il < 2; ++il)
    #pragma unroll
    for (int jn = 0; jn < 8; ++jn) {
      f32x4 a = acc[il][jn];
      #pragma unroll
      for (int r = 0; r < 4; ++r) {
        float s = rcrv[jn] * (a[r] + rclr[il][r] * t2v[jn]);
        a[r] = s;
        M[il][r] = fmaxf(M[il][r], s);
      }
      acc[il][jn] = a;
    }
  #pragma unroll
  for (int o = 1; o < 16; o <<= 1)
    #pragma unroll
    for (int il = 0; il < 2; ++il)
      #pragma unroll
      for (int r = 0; r < 4; ++r)
        M[il][r] = fmaxf(M[il][r], __shfl_xor(M[il][r], o));
  if (c == 0) {
    #pragma unroll
    for (int il = 0; il < 2; ++il)
      #pragma unroll
      for (int r = 0; r < 4; ++r)
        sred[il * 16 + g * 4 + r][w] = M[il][r];
  }
  __syncthreads();
  if (t < 32) {
    float mm = fmaxf(fmaxf(sred[t][0], sred[t][1]), fmaxf(sred[t][2], sred[t][3]));
    sred[t][4] = mm;
  }
  __syncthreads();
  float Mf[2][4];
  #pragma unroll
  for (int il = 0; il < 2; ++il)
    #pragma unroll
    for (int r = 0; r < 4; ++r)
      Mf[il][r] = sred[il * 16 + g * 4 + r][4];
  float S[2][4];
  #pragma unroll
  for (int il = 0; il < 2; ++il)
    #pragma unroll
    for (int r = 0; r < 4; ++r) S[il][r] = 0.f;
  #pragma unroll
  for (int il = 0; il < 2; ++il)
    #pragma unroll
    for (int jn = 0; jn < 8; ++jn) {
      f32x4 a = acc[il][jn];
      #pragma unroll
      for (int r = 0; r < 4; ++r) {
        float e = expf(a[r] - Mf[il][r]);
        a[r] = e;
        S[il][r] += e;
      }
      acc[il][jn] = a;
    }
  #pragma unroll
  for (int o = 1; o < 16; o <<= 1)
    #pragma unroll
    for (int il = 0; il < 2; ++il)
      #pragma unroll
      for (int r = 0; r < 4; ++r)
        S[il][r] += __shfl_xor(S[il][r], o);
  __syncthreads();
  if (c == 0) {
    #pragma unroll
    for (int il = 0; il < 2; ++il)
      #pragma unroll
      for (int r = 0; r < 4; ++r)
        sred[il * 16 + g * 4 + r][w] = S[il][r];
  }
  __syncthreads();
  if (t < 32) {
    float tot = sred[t][0] + sred[t][1] + sred[t][2] + sred[t][3];
    float rs = 1.f / tot;
    sred[t][4] = rs;
    maxv[l0 + t] = rs;
  }
  __syncthreads();
  #pragma unroll
  for (int il = 0; il < 2; ++il) {
    int lt = lt0 + il;
    #pragma unroll
    for (int r = 0; r < 4; ++r) {
      int mrow = g * 4 + r;
      float rs = sred[il * 16 + mrow][4];
      #pragma unroll
      for (int jn = 0; jn < 8; ++jn) {
        int ks = w * 4 + (jn >> 1);
        int gB = (jn * 2 + (c >> 3)) & 3;
        pF[((lt * 16 + ks) * 64 + gB * 16 + mrow) * 8 + (c & 7)] =
            f2bf(acc[il][jn][r] * rs);
      }
    }
  }
}

// ---------------- K3b: degrad (pF @ drlnF) + conv_out (128->384), all MFMA ----------------
__global__ __launch_bounds__(256) void k_deg(const unsigned short* __restrict__ pF,
    const unsigned short* __restrict__ drlnF, const unsigned short* __restrict__ WoF,
    const float* __restrict__ bo, float* __restrict__ out_img) {
  __shared__ float smem[64 * 132];
  int t = threadIdx.x;
  int w = t >> 6, lane = t & 63, c = lane & 15, g = lane >> 4;
  int l0 = blockIdx.x * 64;
  int lt0 = l0 >> 4;
  const short8* P8 = (const short8*)pF;
  const short8* D8 = (const short8*)drlnF;
  const short8* W8 = (const short8*)WoF;
  f32x4 acc[4][2];
  #pragma unroll
  for (int lt = 0; lt < 4; ++lt)
    #pragma unroll
    for (int j2 = 0; j2 < 2; ++j2) acc[lt][j2] = (f32x4){0.f, 0.f, 0.f, 0.f};
  for (int ks = 0; ks < 16; ++ks) {
    short8 a0 = P8[((lt0 + 0) * 16 + ks) * 64 + lane];
    short8 a1 = P8[((lt0 + 1) * 16 + ks) * 64 + lane];
    short8 a2 = P8[((lt0 + 2) * 16 + ks) * 64 + lane];
    short8 a3 = P8[((lt0 + 3) * 16 + ks) * 64 + lane];
    #pragma unroll
    for (int j2 = 0; j2 < 2; ++j2) {
      int dt = w * 2 + j2;
      short8 bh = D8[((dt * 16 + ks) * 2 + 0) * 64 + lane];
      short8 bl = D8[((dt * 16 + ks) * 2 + 1) * 64 + lane];
      acc[0][j2] = __builtin_amdgcn_mfma_f32_16x16x32_bf16(a0, bh, acc[0][j2], 0, 0, 0);
      acc[0][j2] = __builtin_amdgcn_mfma_f32_16x16x32_bf16(a0, bl, acc[0][j2], 0, 0, 0);
      acc[1][j2] = __builtin_amdgcn_mfma_f32_16x16x32_bf16(a1, bh, acc[1][j2], 0, 0, 0);
      acc[1][j2] = __builtin_amdgcn_mfma_f32_16x16x32_bf16(a1, bl, acc[1][j2], 0, 0, 0);
      acc[2][j2] = __builtin_amdgcn_mfma_f32_16x16x32_bf16(a2, bh, acc[2][j2], 0, 0, 0);
      acc[2][j2] = __builtin_amdgcn_mfma_f32_16x16x32_bf16(a2, bl, acc[2][j2], 0, 0, 0);
      acc[3][j2] = __builtin_amdgcn_mfma_f32_16x16x32_bf16(a3, bh, acc[3][j2], 0, 0, 0);
      acc[3][j2] = __builtin_amdgcn_mfma_f32_16x16x32_bf16(a3, bl, acc[3][j2], 0, 0, 0);
    }
  }
  #pragma unroll
  for (int lt = 0; lt < 4; ++lt)
    #pragma unroll
    for (int j2 = 0; j2 < 2; ++j2)
      #pragma unroll
      for (int r = 0; r < 4; ++r)
        smem[(lt * 16 + g * 4 + r) * 132 + w * 32 + j2 * 16 + c] = acc[lt][j2][r];
  __syncthreads();
  f32x4 acc2[4][6];
  #pragma unroll
  for (int lt = 0; lt < 4; ++lt)
    #pragma unroll
    for (int ot = 0; ot < 6; ++ot) acc2[lt][ot] = (f32x4){0.f, 0.f, 0.f, 0.f};
  #pragma unroll
  for (int ks2 = 0; ks2 < 4; ++ks2) {
    short8 dh[4];
    #pragma unroll
    for (int lt = 0; lt < 4; ++lt) {
      const float* src = &smem[(lt * 16 + c) * 132 + ks2 * 32 + g * 8];
      float4 f0 = *(const float4*)src;
      float4 f1 = *(const float4*)(src + 4);
      float vs[8] = {f0.x, f0.y, f0.z, f0.w, f1.x, f1.y, f1.z, f1.w};
      #pragma unroll
      for (int j = 0; j < 8; ++j) dh[lt][j] = (short)f2bf(vs[j]);
    }
    #pragma unroll
    for (int ot = 0; ot < 6; ++ot) {
      int otg = w * 6 + ot;
      short8 wh = W8[((otg * 4 + ks2) * 2 + 0) * 64 + lane];
      short8 wl = W8[((otg * 4 + ks2) * 2 + 1) * 64 + lane];
      #pragma unroll
      for (int lt = 0; lt < 4; ++lt) {
        acc2[lt][ot] = __builtin_amdgcn_mfma_f32_16x16x32_bf16(dh[lt], wh, acc2[lt][ot], 0, 0, 0);
        acc2[lt][ot] = __builtin_amdgcn_mfma_f32_16x16x32_bf16(dh[lt], wl, acc2[lt][ot], 0, 0, 0);
      }
    }
  }
  __syncthreads();
  int b = l0 >> 12, hw0 = l0 & 4095;
  float* ob = out_img + (size_t)b * CIN * HWs + hw0;
  float bov[6];
  #pragma unroll
  for (int ot = 0; ot < 6; ++ot) bov[ot] = bo[w * 96 + ot * 16 + c];
  for (int ot = 0; ot < 6; ++ot) {
    #pragma unroll
    for (int lt = 0; lt < 4; ++lt)
      #pragma unroll
      for (int r = 0; r < 4; ++r)
        smem[(lt * 16 + g * 4 + r) * 65 + w * 16 + c] = acc2[lt][ot][r] + bov[ot];
    __syncthreads();
    #pragma unroll
    for (int i = 0; i < 16; ++i) {
      int idx = t + i * 256;
      int o_l = idx >> 6, ll = idx & 63;
      int o = (o_l >> 4) * 96 + ot * 16 + (o_l & 15);
      ob[(size_t)o * HWs + ll] = smem[ll * 65 + o_l];
    }
    __syncthreads();
  }
}

// ---------------- K4: mask ----------------
__global__ __launch_bounds__(256) void k_mask(const float* __restrict__ maxv,
                                              float* __restrict__ outm) {
  int b = blockIdx.x, t = threadIdx.x;
  float c[16];
  float mn = 1e30f, mx = -1e30f;
  #pragma unroll
  for (int j = 0; j < 16; ++j) {
    float x = maxv[b * HWs + t + j * 256];
    float cc = x * x * x;
    c[j] = cc;
    mn = fminf(mn, cc); mx = fmaxf(mx, cc);
  }
  #pragma unroll
  for (int o = 32; o; o >>= 1) { mn = fminf(mn, __shfl_xor(mn, o)); mx = fmaxf(mx, __shfl_xor(mx, o)); }
  __shared__ float smn[4], smx[4];
  int w = t >> 6;
  if ((t & 63) == 0) { smn[w] = mn; smx[w] = mx; }
  __syncthreads();
  mn = fminf(fminf(smn[0], smn[1]), fminf(smn[2], smn[3]));
  mx = fmaxf(fmaxf(smx[0], smx[1]), fmaxf(smx[2], smx[3]));
  float sc = 1.f / (mx - mn);
  #pragma unroll
  for (int j = 0; j < 16; ++j)
    outm[b * HWs + t + j * 256] = 1.f - (c[j] - mn) * sc;
}

// ---------------- K5: top-81 ----------------
__global__ __launch_bounds__(256) void k_topk(const float* __restrict__ maxv,
                                              int* __restrict__ tix) {
  int b = blockIdx.x, t = threadIdx.x;
  unsigned long long key[16];
  #pragma unroll
  for (int j = 0; j < 16; ++j) {
    int idx = t + j * 256;
    unsigned int bits = __float_as_uint(maxv[b * HWs + idx]);
    key[j] = ((unsigned long long)bits << 32) | (unsigned int)(4095 - idx);
  }
  __shared__ unsigned long long wbest[4];
  for (int k = 0; k < TOPK; ++k) {
    unsigned long long best = 0ull;
    #pragma unroll
    for (int j = 0; j < 16; ++j) if (key[j] > best) best = key[j];
    #pragma unroll
    for (int o = 32; o; o >>= 1) {
      unsigned long long ot = __shfl_xor(best, o);
      if (ot > best) best = ot;
    }
    __syncthreads();
    if ((t & 63) == 0) wbest[t >> 6] = best;
    __syncthreads();
    unsigned long long B0 = wbest[0];
    if (wbest[1] > B0) B0 = wbest[1];
    if (wbest[2] > B0) B0 = wbest[2];
    if (wbest[3] > B0) B0 = wbest[3];
    int idx = 4095 - (int)(B0 & 0xFFFFFFFFull);
    if (t == 0) tix[b * TOPK + k] = idx;
    #pragma unroll
    for (int j = 0; j < 16; ++j) if ((t + j * 256) == idx) key[j] = 0ull;
  }
}

// ---------------- K6: gather ----------------
__global__ __launch_bounds__(128) void k_gather(const unsigned short* __restrict__ pF,
    const int* __restrict__ tix, float* __restrict__ outr) {
  int gB_ = blockIdx.x;
  int k = gB_ % TOPK;
  int bb = gB_ / TOPK;
  int b2 = bb & 7, b = bb >> 3;
  int l = b * HWs + tix[b2 * TOPK + k];
  int lt = l >> 4, mrow = l & 15;
  int t = threadIdx.x;
  int ks = t >> 3, gq = (t >> 1) & 3, j0 = (t & 1) * 4;
  int base = ((lt * 16 + ks) * 64 + gq * 16 + mrow) * 8 + j0;
  const unsigned* src = (const unsigned*)(pF + base);
  unsigned u0 = src[0], u1 = src[1];
  float4 v = {bf2f(u0 & 0xffffu), bf2f(u0 >> 16), bf2f(u1 & 0xffffu), bf2f(u1 >> 16)};
  *(float4*)(outr + (size_t)gB_ * NN + t * 4) = v;
}

extern "C" void kernel_launch(void* const* d_in, const int* in_sizes, int n_in,
                              void* d_out, int out_size, void* d_ws, size_t ws_size,
                              hipStream_t stream) {
  const float* x    = (const float*)d_in[0];
  const float* DR   = (const float*)d_in[1];
  const float* win  = (const float*)d_in[2];
  const float* bin  = (const float*)d_in[3];
  const float* sw   = (const float*)d_in[4];
  const float* sb   = (const float*)d_in[5];
  const float* n1w  = (const float*)d_in[6];
  const float* n1b  = (const float*)d_in[7];
  const float* n2w  = (const float*)d_in[8];
  const float* n2b  = (const float*)d_in[9];
  const float* wout = (const float*)d_in[10];
  const float* bout = (const float*)d_in[11];
  float* out = (float*)d_out;
  float* W = (float*)d_ws;

  // workspace layout (float offsets), ~68.4 MB
  unsigned short* drwF  = (unsigned short*)(W);            // 65536 f
  float* t2   = W + 65536;                                 // 512
  float* rcr  = W + 66048;                                 // 512
  float* rclv = W + 66560;                                 // 32768
  float* maxv = W + 99328;                                 // 32768
  unsigned short* drlnF = (unsigned short*)(W + 132096);   // 65536 f
  unsigned short* WoF   = (unsigned short*)(W + 197632);   // 49152 f
  unsigned short* WinF  = (unsigned short*)(W + 246784);   // 49152 f
  unsigned short* semWF = (unsigned short*)(W + 295936);   // 16384 f
  unsigned short* ApF   = (unsigned short*)(W + 312320);   // 4194304 f
  unsigned short* xaF   = (unsigned short*)(W + 4506624);  // 4194304 f (dead after k_sem)
  unsigned short* pF    = (unsigned short*)(W + 4506624);  // 8388608 f (aliases xaF)
  int*   tix  = (int*)(W + 12895232);                      // 648 ints

  float* out_mask = out;
  float* out_img  = out + 32768;
  float* out_res  = out + 32768 + 12582912;

  k_dr    <<<NN, 64, 0, stream>>>(DR, n2w, n2b, n1w, n1b, drwF, drlnF, t2, rcr);
  k_bprep <<<dim3(8, 3),  256, 0, stream>>>(win,  WinF,  CIN);   // Win  [128,384]
  k_bprep <<<dim3(8, 1),  256, 0, stream>>>(sw,   semWF, DD);    // semW [128,128]
  k_bprep <<<dim3(24, 1), 256, 0, stream>>>(wout, WoF,   DD);    // Wo   [384,128]
  k_convin<<<512,  256, 0, stream>>>(x, WinF, bin, xaF);
  k_sem   <<<512,  256, 0, stream>>>(xaF, semWF, sb, n1w, n1b, ApF, rclv);
  k_scores<<<1024, 256, 0, stream>>>(ApF, drwF, t2, rcr, rclv, pF, maxv);
  k_deg   <<<512,  256, 0, stream>>>(pF, drlnF, WoF, bout, out_img);
  k_mask  <<<BB,   256, 0, stream>>>(maxv, out_mask);
  k_topk  <<<BB,   256, 0, stream>>>(maxv, tix);
  k_gather<<<BB * BB * TOPK, 128, 0, stream>>>(pF, tix, out_res);
}

// Round 5
// 250.133 us; speedup vs baseline: 2.3367x; 1.1723x over previous
//
#include <hip/hip_runtime.h>
#include <cstdint>

#define EPS 1e-5f
#define BB   8
#define CIN  384
#define HWs  4096
#define LT   32768
#define DD   128
#define NN   512
#define TOPK 81

typedef short short8 __attribute__((ext_vector_type(8)));   // 8 bf16 (4 VGPRs)
typedef float f32x4  __attribute__((ext_vector_type(4)));

__device__ __forceinline__ unsigned short f2bf(float x) {   // RNE, finite inputs
  unsigned u = __float_as_uint(x);
  u += 0x7fffu + ((u >> 16) & 1u);
  return (unsigned short)(u >> 16);
}
__device__ __forceinline__ float bf2f(unsigned u16) {
  return __uint_as_float(u16 << 16);
}
// write element (row rc in tile, k) of an operand as hi/lo bf16 in MFMA frag order.
// frag layout (HW-verified R1-R3): lane=((k>>3)&3)*16 + rc, j=k&7.
__device__ __forceinline__ void put_frag(unsigned short* buf, int tile, int rc, int k, float v) {
  int ks = k >> 5, g = (k >> 3) & 3, j = k & 7;
  int basehw = ((tile * 4 + ks) * 2) * 512 + (g * 16 + rc) * 8 + j;
  unsigned short hi = f2bf(v);
  buf[basehw] = hi;
  buf[basehw + 512] = f2bf(v - bf2f(hi));
}

// ---------------- K0: DR layernorm prep ----------------
__global__ __launch_bounds__(64) void k_dr(const float* __restrict__ DR,
    const float* __restrict__ w2, const float* __restrict__ b2,
    const float* __restrict__ w1, const float* __restrict__ b1,
    unsigned short* __restrict__ drwF, unsigned short* __restrict__ drlnF,
    float* __restrict__ t2, float* __restrict__ rcr) {
  int n = blockIdx.x;
  int lane = threadIdx.x;
  const float* row = DR + n * DD;
  float x0 = row[lane], x1 = row[lane + 64];
  float s = x0 + x1, sq = x0 * x0 + x1 * x1;
  #pragma unroll
  for (int o = 32; o; o >>= 1) { s += __shfl_xor(s, o); sq += __shfl_xor(sq, o); }
  float m = s * (1.f / 128.f);
  float v = sq * (1.f / 128.f) - m * m;
  float inv = rsqrtf(v + EPS);
  float y0 = (x0 - m) * inv * w2[lane] + b2[lane];
  float y1 = (x1 - m) * inv * w2[lane + 64] + b2[lane + 64];
  // drwF: B-frag col=n, k=d (nkt=4)
  int nt = n >> 4, cc = n & 15;
  put_frag(drwF, nt, cc, lane, y0 * w1[lane]);
  put_frag(drwF, nt, cc, lane + 64, y1 * w1[lane + 64]);
  // drlnF: B-frag col=d, k=n (nkt=16)
  int ks = n >> 5, gB = (n >> 3) & 3, j = n & 7;
  {
    int d = lane;
    unsigned short hi = f2bf(y0);
    int base = (((d >> 4) * 16 + ks) * 2) * 512 + (gB * 16 + (d & 15)) * 8 + j;
    drlnF[base] = hi;
    drlnF[base + 512] = f2bf(y0 - bf2f(hi));
  }
  {
    int d = lane + 64;
    unsigned short hi = f2bf(y1);
    int base = (((d >> 4) * 16 + ks) * 2) * 512 + (gB * 16 + (d & 15)) * 8 + j;
    drlnF[base] = hi;
    drlnF[base + 512] = f2bf(y1 - bf2f(hi));
  }
  float pt2 = y0 * b1[lane] + y1 * b1[lane + 64];
  float pss = y0 * y0 + y1 * y1;
  #pragma unroll
  for (int o = 32; o; o >>= 1) { pt2 += __shfl_xor(pt2, o); pss += __shfl_xor(pss, o); }
  if (lane == 0) { t2[n] = pt2; rcr[n] = rsqrtf(pss); }
}

// ---------------- K0b: generic [R,K] row-major -> B-frag hi/lo (col=r, k) --------
__global__ __launch_bounds__(256) void k_bprep(const float* __restrict__ src,
                                               unsigned short* __restrict__ dst,
                                               int K) {
  int rt = blockIdx.x, kb = blockIdx.y;
  int t = threadIdx.x, m = t >> 4, kg = t & 15;
  int k0 = kb * 128 + kg * 8;
  const float* s = src + (size_t)(rt * 16 + m) * K + k0;
  float4 f0 = *(const float4*)s;
  float4 f1 = *(const float4*)(s + 4);
  float vs[8] = {f0.x, f0.y, f0.z, f0.w, f1.x, f1.y, f1.z, f1.w};
  short8 hi, lo;
  #pragma unroll
  for (int j = 0; j < 8; ++j) {
    unsigned short h = f2bf(vs[j]);
    hi[j] = (short)h;
    lo[j] = (short)f2bf(vs[j] - bf2f(h));
  }
  int nkt = K >> 5;
  int ks = k0 >> 5, g = (k0 >> 3) & 3;
  short8* D8 = (short8*)dst;
  int base = ((rt * nkt + ks) * 2) * 64 + g * 16 + m;
  D8[base] = hi;
  D8[base + 64] = lo;
}

// ---------------- K1: conv_in (384 -> 128), split-bf16 MFMA ----------------
__global__ __launch_bounds__(256) void k_convin(const float* __restrict__ x,
    const unsigned short* __restrict__ WinF, const float* __restrict__ bias,
    unsigned short* __restrict__ xaF) {
  __shared__ float smem[64 * 132];
  int t = threadIdx.x;
  int w = t >> 6, lane = t & 63, m = lane & 15, g = lane >> 4;
  int l0 = blockIdx.x * 64;
  int b = l0 >> 12, hw0 = l0 & 4095;
  const float* xb = x + (size_t)b * CIN * HWs + hw0;
  const short8* B8 = (const short8*)WinF;
  f32x4 acc[4][2];
  #pragma unroll
  for (int lt = 0; lt < 4; ++lt)
    #pragma unroll
    for (int j2 = 0; j2 < 2; ++j2) acc[lt][j2] = (f32x4){0.f, 0.f, 0.f, 0.f};
  for (int ks = 0; ks < 12; ++ks) {
    short8 ah[4], al[4];
    const float* xc = xb + (size_t)(ks * 32 + g * 8) * HWs;
    #pragma unroll
    for (int lt = 0; lt < 4; ++lt) {
      const float* xcl = xc + lt * 16 + m;
      float v[8];
      #pragma unroll
      for (int j = 0; j < 8; ++j) v[j] = xcl[(size_t)j * HWs];
      #pragma unroll
      for (int j = 0; j < 8; ++j) {
        unsigned short h = f2bf(v[j]);
        ah[lt][j] = (short)h;
        al[lt][j] = (short)f2bf(v[j] - bf2f(h));
      }
    }
    #pragma unroll
    for (int j2 = 0; j2 < 2; ++j2) {
      int dt = w * 2 + j2;
      short8 bh = B8[((dt * 12 + ks) * 2 + 0) * 64 + lane];
      short8 bl = B8[((dt * 12 + ks) * 2 + 1) * 64 + lane];
      #pragma unroll
      for (int lt = 0; lt < 4; ++lt) {
        acc[lt][j2] = __builtin_amdgcn_mfma_f32_16x16x32_bf16(ah[lt], bh, acc[lt][j2], 0, 0, 0);
        acc[lt][j2] = __builtin_amdgcn_mfma_f32_16x16x32_bf16(ah[lt], bl, acc[lt][j2], 0, 0, 0);
        acc[lt][j2] = __builtin_amdgcn_mfma_f32_16x16x32_bf16(al[lt], bh, acc[lt][j2], 0, 0, 0);
      }
    }
  }
  float bia[2] = {bias[w * 32 + m], bias[w * 32 + 16 + m]};
  #pragma unroll
  for (int lt = 0; lt < 4; ++lt)
    #pragma unroll
    for (int j2 = 0; j2 < 2; ++j2)
      #pragma unroll
      for (int r = 0; r < 4; ++r)
        smem[(lt * 16 + g * 4 + r) * 132 + (w * 2 + j2) * 16 + m] = acc[lt][j2][r] + bia[j2];
  __syncthreads();
  short8* X8 = (short8*)xaF;
  #pragma unroll
  for (int it = 0; it < 4; ++it) {
    int idx = it * 256 + t;
    int l = idx & 63, dq = idx >> 6;
    const float* src = &smem[l * 132 + dq * 8];
    float4 f0 = *(const float4*)src;
    float4 f1 = *(const float4*)(src + 4);
    float vs[8] = {f0.x, f0.y, f0.z, f0.w, f1.x, f1.y, f1.z, f1.w};
    short8 hi, lo;
    #pragma unroll
    for (int j = 0; j < 8; ++j) {
      unsigned short h = f2bf(vs[j]);
      hi[j] = (short)h;
      lo[j] = (short)f2bf(vs[j] - bf2f(h));
    }
    int ltg = (l0 + l) >> 4;
    int idx8 = ((ltg * 4 + (dq >> 2)) * 2) * 64 + (dq & 3) * 16 + (l & 15);
    X8[idx8] = hi;
    X8[idx8 + 64] = lo;
  }
}

// ---------------- K2: sem conv (128->128) MFMA + LN1 + 2nd-LN fold ----------------
__global__ __launch_bounds__(256) void k_sem(const unsigned short* __restrict__ xaF,
    const unsigned short* __restrict__ semWF, const float* __restrict__ bias,
    const float* __restrict__ w1, const float* __restrict__ b1,
    unsigned short* __restrict__ ApF, float* __restrict__ rclv) {
  __shared__ float smem[64 * 132];
  __shared__ float sredS[64][4], sredQ[64][4];
  __shared__ float rowM[64], rowI[64];
  int t = threadIdx.x;
  int w = t >> 6, lane = t & 63, m = lane & 15, g = lane >> 4;
  int l0 = blockIdx.x * 64;
  int lt0 = l0 >> 4;
  const short8* A8 = (const short8*)xaF;
  const short8* B8 = (const short8*)semWF;
  f32x4 acc[4][2];
  #pragma unroll
  for (int lt = 0; lt < 4; ++lt)
    #pragma unroll
    for (int j2 = 0; j2 < 2; ++j2) acc[lt][j2] = (f32x4){0.f, 0.f, 0.f, 0.f};
  #pragma unroll
  for (int ks = 0; ks < 4; ++ks) {
    short8 ah[4], al[4];
    #pragma unroll
    for (int lt = 0; lt < 4; ++lt) {
      ah[lt] = A8[(((lt0 + lt) * 4 + ks) * 2 + 0) * 64 + lane];
      al[lt] = A8[(((lt0 + lt) * 4 + ks) * 2 + 1) * 64 + lane];
    }
    #pragma unroll
    for (int j2 = 0; j2 < 2; ++j2) {
      int dt = w * 2 + j2;
      short8 bh = B8[((dt * 4 + ks) * 2 + 0) * 64 + lane];
      short8 bl = B8[((dt * 4 + ks) * 2 + 1) * 64 + lane];
      #pragma unroll
      for (int lt = 0; lt < 4; ++lt) {
        acc[lt][j2] = __builtin_amdgcn_mfma_f32_16x16x32_bf16(ah[lt], bh, acc[lt][j2], 0, 0, 0);
        acc[lt][j2] = __builtin_amdgcn_mfma_f32_16x16x32_bf16(ah[lt], bl, acc[lt][j2], 0, 0, 0);
        acc[lt][j2] = __builtin_amdgcn_mfma_f32_16x16x32_bf16(al[lt], bh, acc[lt][j2], 0, 0, 0);
      }
    }
  }
  float bia[2] = {bias[w * 32 + m], bias[w * 32 + 16 + m]};
  #pragma unroll
  for (int lt = 0; lt < 4; ++lt)
    #pragma unroll
    for (int j2 = 0; j2 < 2; ++j2)
      #pragma unroll
      for (int r = 0; r < 4; ++r) acc[lt][j2][r] += bia[j2];
  float s1[4][4], q1[4][4];
  #pragma unroll
  for (int lt = 0; lt < 4; ++lt)
    #pragma unroll
    for (int r = 0; r < 4; ++r) {
      float a = acc[lt][0][r], b2v = acc[lt][1][r];
      s1[lt][r] = a + b2v;
      q1[lt][r] = a * a + b2v * b2v;
    }
  #pragma unroll
  for (int o = 1; o < 16; o <<= 1)
    #pragma unroll
    for (int lt = 0; lt < 4; ++lt)
      #pragma unroll
      for (int r = 0; r < 4; ++r) {
        s1[lt][r] += __shfl_xor(s1[lt][r], o);
        q1[lt][r] += __shfl_xor(q1[lt][r], o);
      }
  if (m == 0) {
    #pragma unroll
    for (int lt = 0; lt < 4; ++lt)
      #pragma unroll
      for (int r = 0; r < 4; ++r) {
        sredS[lt * 16 + g * 4 + r][w] = s1[lt][r];
        sredQ[lt * 16 + g * 4 + r][w] = q1[lt][r];
      }
  }
  __syncthreads();
  if (t < 64) {
    float S = sredS[t][0] + sredS[t][1] + sredS[t][2] + sredS[t][3];
    float Q = sredQ[t][0] + sredQ[t][1] + sredQ[t][2] + sredQ[t][3];
    float mu = S * (1.f / 128.f);
    float var = Q * (1.f / 128.f) - mu * mu;
    rowM[t] = mu;
    rowI[t] = rsqrtf(var + EPS);
  }
  __syncthreads();
  float w1v[2] = {w1[w * 32 + m], w1[w * 32 + 16 + m]};
  float b1v[2] = {b1[w * 32 + m], b1[w * 32 + 16 + m]};
  #pragma unroll
  for (int lt = 0; lt < 4; ++lt)
    #pragma unroll
    for (int r = 0; r < 4; ++r) {
      float mu = rowM[lt * 16 + g * 4 + r];
      float iv = rowI[lt * 16 + g * 4 + r];
      float y0 = (acc[lt][0][r] - mu) * iv * w1v[0] + b1v[0];
      float y1 = (acc[lt][1][r] - mu) * iv * w1v[1] + b1v[1];
      acc[lt][0][r] = y0; acc[lt][1][r] = y1;
      s1[lt][r] = y0 + y1;
      q1[lt][r] = y0 * y0 + y1 * y1;
    }
  #pragma unroll
  for (int o = 1; o < 16; o <<= 1)
    #pragma unroll
    for (int lt = 0; lt < 4; ++lt)
      #pragma unroll
      for (int r = 0; r < 4; ++r) {
        s1[lt][r] += __shfl_xor(s1[lt][r], o);
        q1[lt][r] += __shfl_xor(q1[lt][r], o);
      }
  if (m == 0) {
    #pragma unroll
    for (int lt = 0; lt < 4; ++lt)
      #pragma unroll
      for (int r = 0; r < 4; ++r) {
        sredS[lt * 16 + g * 4 + r][w] = s1[lt][r];
        sredQ[lt * 16 + g * 4 + r][w] = q1[lt][r];
      }
  }
  __syncthreads();
  if (t < 64) {
    float S = sredS[t][0] + sredS[t][1] + sredS[t][2] + sredS[t][3];
    float Q = sredQ[t][0] + sredQ[t][1] + sredQ[t][2] + sredQ[t][3];
    float m2 = S * (1.f / 128.f);
    float v2 = Q * (1.f / 128.f) - m2 * m2;
    float inv2 = rsqrtf(v2 + EPS);
    float rcl = rsqrtf(Q);
    rowM[t] = m2;
    rowI[t] = inv2 * rcl;
    rclv[l0 + t] = rcl;
  }
  __syncthreads();
  #pragma unroll
  for (int lt = 0; lt < 4; ++lt)
    #pragma unroll
    for (int r = 0; r < 4; ++r) {
      float m2 = rowM[lt * 16 + g * 4 + r];
      float sc = rowI[lt * 16 + g * 4 + r];
      smem[(lt * 16 + g * 4 + r) * 132 + w * 32 + m] = (acc[lt][0][r] - m2) * sc;
      smem[(lt * 16 + g * 4 + r) * 132 + w * 32 + 16 + m] = (acc[lt][1][r] - m2) * sc;
    }
  __syncthreads();
  short8* O8 = (short8*)ApF;
  #pragma unroll
  for (int it = 0; it < 4; ++it) {
    int idx = it * 256 + t;
    int l = idx & 63, dq = idx >> 6;
    const float* src = &smem[l * 132 + dq * 8];
    float4 f0 = *(const float4*)src;
    float4 f1 = *(const float4*)(src + 4);
    float vs[8] = {f0.x, f0.y, f0.z, f0.w, f1.x, f1.y, f1.z, f1.w};
    short8 hi, lo;
    #pragma unroll
    for (int j = 0; j < 8; ++j) {
      unsigned short h = f2bf(vs[j]);
      hi[j] = (short)h;
      lo[j] = (short)f2bf(vs[j] - bf2f(h));
    }
    int ltg = (l0 + l) >> 4;
    int idx8 = ((ltg * 4 + (dq >> 2)) * 2) * 64 + (dq & 3) * 16 + (l & 15);
    O8[idx8] = hi;
    O8[idx8 + 64] = lo;
  }
}

// ---------------- K3a: scores + softmax (split-bf16 MFMA) ----------------
__global__ __launch_bounds__(256) void k_scores(const unsigned short* __restrict__ ApF,
    const unsigned short* __restrict__ drwF, const float* __restrict__ t2g,
    const float* __restrict__ rcrg, const float* __restrict__ rclg,
    unsigned short* __restrict__ pF, float* __restrict__ maxv) {
  __shared__ float sred[32][5];
  int t = threadIdx.x;
  int w = t >> 6, lane = t & 63, c = lane & 15, g = lane >> 4;
  int l0 = blockIdx.x * 32;
  int lt0 = blockIdx.x * 2;
  const short8* A8 = (const short8*)ApF;
  const short8* B8 = (const short8*)drwF;
  f32x4 acc[2][8];
  #pragma unroll
  for (int il = 0; il < 2; ++il)
    #pragma unroll
    for (int jn = 0; jn < 8; ++jn) acc[il][jn] = (f32x4){0.f, 0.f, 0.f, 0.f};
  #pragma unroll
  for (int ks = 0; ks < 4; ++ks) {
    short8 ah0 = A8[((lt0 * 4 + ks) * 2 + 0) * 64 + lane];
    short8 al0 = A8[((lt0 * 4 + ks) * 2 + 1) * 64 + lane];
    short8 ah1 = A8[(((lt0 + 1) * 4 + ks) * 2 + 0) * 64 + lane];
    short8 al1 = A8[(((lt0 + 1) * 4 + ks) * 2 + 1) * 64 + lane];
    #pragma unroll
    for (int jn = 0; jn < 8; ++jn) {
      int nt = w * 8 + jn;
      short8 bh = B8[((nt * 4 + ks) * 2 + 0) * 64 + lane];
      short8 bl = B8[((nt * 4 + ks) * 2 + 1) * 64 + lane];
      acc[0][jn] = __builtin_amdgcn_mfma_f32_16x16x32_bf16(ah0, bh, acc[0][jn], 0, 0, 0);
      acc[0][jn] = __builtin_amdgcn_mfma_f32_16x16x32_bf16(ah0, bl, acc[0][jn], 0, 0, 0);
      acc[0][jn] = __builtin_amdgcn_mfma_f32_16x16x32_bf16(al0, bh, acc[0][jn], 0, 0, 0);
      acc[1][jn] = __builtin_amdgcn_mfma_f32_16x16x32_bf16(ah1, bh, acc[1][jn], 0, 0, 0);
      acc[1][jn] = __builtin_amdgcn_mfma_f32_16x16x32_bf16(ah1, bl, acc[1][jn], 0, 0, 0);
      acc[1][jn] = __builtin_amdgcn_mfma_f32_16x16x32_bf16(al1, bh, acc[1][jn], 0, 0, 0);
    }
  }
  float rcrv[8], t2v[8];
  #pragma unroll
  for (int jn = 0; jn < 8; ++jn) {
    int n = w * 128 + jn * 16 + c;
    rcrv[jn] = rcrg[n]; t2v[jn] = t2g[n];
  }
  float rclr[2][4];
  #pragma unroll
  for (int il = 0; il < 2; ++il)
    #pragma unroll
    for (int r = 0; r < 4; ++r)
      rclr[il][r] = rclg[l0 + il * 16 + g * 4 + r];
  float M[2][4];
  #pragma unroll
  for (int il = 0; il < 2; ++il)
    #pragma unroll
    for (int r = 0; r < 4; ++r) M[il][r] = -1e30f;
  #pragma unroll
  for (int il = 0; il < 2; ++il)
    #pragma unroll
    for (int jn = 0; jn < 8; ++jn) {
      f32x4 a = acc[il][jn];
      #pragma unroll
      for (int r = 0; r < 4; ++r) {
        float s = rcrv[jn] * (a[r] + rclr[il][r] * t2v[jn]);
        a[r] = s;
        M[il][r] = fmaxf(M[il][r], s);
      }
      acc[il][jn] = a;
    }
  #pragma unroll
  for (int o = 1; o < 16; o <<= 1)
    #pragma unroll
    for (int il = 0; il < 2; ++il)
      #pragma unroll
      for (int r = 0; r < 4; ++r)
        M[il][r] = fmaxf(M[il][r], __shfl_xor(M[il][r], o));
  if (c == 0) {
    #pragma unroll
    for (int il = 0; il < 2; ++il)
      #pragma unroll
      for (int r = 0; r < 4; ++r)
        sred[il * 16 + g * 4 + r][w] = M[il][r];
  }
  __syncthreads();
  if (t < 32) {
    float mm = fmaxf(fmaxf(sred[t][0], sred[t][1]), fmaxf(sred[t][2], sred[t][3]));
    sred[t][4] = mm;
  }
  __syncthreads();
  float Mf[2][4];
  #pragma unroll
  for (int il = 0; il < 2; ++il)
    #pragma unroll
    for (int r = 0; r < 4; ++r)
      Mf[il][r] = sred[il * 16 + g * 4 + r][4];
  float S[2][4];
  #pragma unroll
  for (int il = 0; il < 2; ++il)
    #pragma unroll
    for (int r = 0; r < 4; ++r) S[il][r] = 0.f;
  #pragma unroll
  for (int il = 0; il < 2; ++il)
    #pragma unroll
    for (int jn = 0; jn < 8; ++jn) {
      f32x4 a = acc[il][jn];
      #pragma unroll
      for (int r = 0; r < 4; ++r) {
        float e = expf(a[r] - Mf[il][r]);
        a[r] = e;
        S[il][r] += e;
      }
      acc[il][jn] = a;
    }
  #pragma unroll
  for (int o = 1; o < 16; o <<= 1)
    #pragma unroll
    for (int il = 0; il < 2; ++il)
      #pragma unroll
      for (int r = 0; r < 4; ++r)
        S[il][r] += __shfl_xor(S[il][r], o);
  __syncthreads();
  if (c == 0) {
    #pragma unroll
    for (int il = 0; il < 2; ++il)
      #pragma unroll
      for (int r = 0; r < 4; ++r)
        sred[il * 16 + g * 4 + r][w] = S[il][r];
  }
  __syncthreads();
  if (t < 32) {
    float tot = sred[t][0] + sred[t][1] + sred[t][2] + sred[t][3];
    float rs = 1.f / tot;
    sred[t][4] = rs;
    maxv[l0 + t] = rs;
  }
  __syncthreads();
  #pragma unroll
  for (int il = 0; il < 2; ++il) {
    int lt = lt0 + il;
    #pragma unroll
    for (int r = 0; r < 4; ++r) {
      int mrow = g * 4 + r;
      float rs = sred[il * 16 + mrow][4];
      #pragma unroll
      for (int jn = 0; jn < 8; ++jn) {
        int ks = w * 4 + (jn >> 1);
        int gB = (jn * 2 + (c >> 3)) & 3;
        pF[((lt * 16 + ks) * 64 + gB * 16 + mrow) * 8 + (c & 7)] =
            f2bf(acc[il][jn][r] * rs);
      }
    }
  }
}

// ---------------- K3b: degrad (pF @ drlnF) + conv_out (128->384), all MFMA ----------------
__global__ __launch_bounds__(256) void k_deg(const unsigned short* __restrict__ pF,
    const unsigned short* __restrict__ drlnF, const unsigned short* __restrict__ WoF,
    const float* __restrict__ bo, float* __restrict__ out_img) {
  __shared__ float smem[64 * 132];
  int t = threadIdx.x;
  int w = t >> 6, lane = t & 63, c = lane & 15, g = lane >> 4;
  int l0 = blockIdx.x * 64;
  int lt0 = l0 >> 4;
  const short8* P8 = (const short8*)pF;
  const short8* D8 = (const short8*)drlnF;
  const short8* W8 = (const short8*)WoF;
  f32x4 acc[4][2];
  #pragma unroll
  for (int lt = 0; lt < 4; ++lt)
    #pragma unroll
    for (int j2 = 0; j2 < 2; ++j2) acc[lt][j2] = (f32x4){0.f, 0.f, 0.f, 0.f};
  for (int ks = 0; ks < 16; ++ks) {
    short8 a0 = P8[((lt0 + 0) * 16 + ks) * 64 + lane];
    short8 a1 = P8[((lt0 + 1) * 16 + ks) * 64 + lane];
    short8 a2 = P8[((lt0 + 2) * 16 + ks) * 64 + lane];
    short8 a3 = P8[((lt0 + 3) * 16 + ks) * 64 + lane];
    #pragma unroll
    for (int j2 = 0; j2 < 2; ++j2) {
      int dt = w * 2 + j2;
      short8 bh = D8[((dt * 16 + ks) * 2 + 0) * 64 + lane];
      short8 bl = D8[((dt * 16 + ks) * 2 + 1) * 64 + lane];
      acc[0][j2] = __builtin_amdgcn_mfma_f32_16x16x32_bf16(a0, bh, acc[0][j2], 0, 0, 0);
      acc[0][j2] = __builtin_amdgcn_mfma_f32_16x16x32_bf16(a0, bl, acc[0][j2], 0, 0, 0);
      acc[1][j2] = __builtin_amdgcn_mfma_f32_16x16x32_bf16(a1, bh, acc[1][j2], 0, 0, 0);
      acc[1][j2] = __builtin_amdgcn_mfma_f32_16x16x32_bf16(a1, bl, acc[1][j2], 0, 0, 0);
      acc[2][j2] = __builtin_amdgcn_mfma_f32_16x16x32_bf16(a2, bh, acc[2][j2], 0, 0, 0);
      acc[2][j2] = __builtin_amdgcn_mfma_f32_16x16x32_bf16(a2, bl, acc[2][j2], 0, 0, 0);
      acc[3][j2] = __builtin_amdgcn_mfma_f32_16x16x32_bf16(a3, bh, acc[3][j2], 0, 0, 0);
      acc[3][j2] = __builtin_amdgcn_mfma_f32_16x16x32_bf16(a3, bl, acc[3][j2], 0, 0, 0);
    }
  }
  #pragma unroll
  for (int lt = 0; lt < 4; ++lt)
    #pragma unroll
    for (int j2 = 0; j2 < 2; ++j2)
      #pragma unroll
      for (int r = 0; r < 4; ++r)
        smem[(lt * 16 + g * 4 + r) * 132 + w * 32 + j2 * 16 + c] = acc[lt][j2][r];
  __syncthreads();
  f32x4 acc2[4][6];
  #pragma unroll
  for (int lt = 0; lt < 4; ++lt)
    #pragma unroll
    for (int ot = 0; ot < 6; ++ot) acc2[lt][ot] = (f32x4){0.f, 0.f, 0.f, 0.f};
  #pragma unroll
  for (int ks2 = 0; ks2 < 4; ++ks2) {
    short8 dh[4];
    #pragma unroll
    for (int lt = 0; lt < 4; ++lt) {
      const float* src = &smem[(lt * 16 + c) * 132 + ks2 * 32 + g * 8];
      float4 f0 = *(const float4*)src;
      float4 f1 = *(const float4*)(src + 4);
      float vs[8] = {f0.x, f0.y, f0.z, f0.w, f1.x, f1.y, f1.z, f1.w};
      #pragma unroll
      for (int j = 0; j < 8; ++j) dh[lt][j] = (short)f2bf(vs[j]);
    }
    #pragma unroll
    for (int ot = 0; ot < 6; ++ot) {
      int otg = w * 6 + ot;
      short8 wh = W8[((otg * 4 + ks2) * 2 + 0) * 64 + lane];
      short8 wl = W8[((otg * 4 + ks2) * 2 + 1) * 64 + lane];
      #pragma unroll
      for (int lt = 0; lt < 4; ++lt) {
        acc2[lt][ot] = __builtin_amdgcn_mfma_f32_16x16x32_bf16(dh[lt], wh, acc2[lt][ot], 0, 0, 0);
        acc2[lt][ot] = __builtin_amdgcn_mfma_f32_16x16x32_bf16(dh[lt], wl, acc2[lt][ot], 0, 0, 0);
      }
    }
  }
  __syncthreads();
  int b = l0 >> 12, hw0 = l0 & 4095;
  float* ob = out_img + (size_t)b * CIN * HWs + hw0;
  float bov[6];
  #pragma unroll
  for (int ot = 0; ot < 6; ++ot) bov[ot] = bo[w * 96 + ot * 16 + c];
  for (int ot = 0; ot < 6; ++ot) {
    #pragma unroll
    for (int lt = 0; lt < 4; ++lt)
      #pragma unroll
      for (int r = 0; r < 4; ++r)
        smem[(lt * 16 + g * 4 + r) * 65 + w * 16 + c] = acc2[lt][ot][r] + bov[ot];
    __syncthreads();
    #pragma unroll
    for (int i = 0; i < 16; ++i) {
      int idx = t + i * 256;
      int o_l = idx >> 6, ll = idx & 63;
      int o = (o_l >> 4) * 96 + ot * 16 + (o_l & 15);
      ob[(size_t)o * HWs + ll] = smem[ll * 65 + o_l];
    }
    __syncthreads();
  }
}

// ---------------- K4: mask ----------------
__global__ __launch_bounds__(256) void k_mask(const float* __restrict__ maxv,
                                              float* __restrict__ outm) {
  int b = blockIdx.x, t = threadIdx.x;
  float c[16];
  float mn = 1e30f, mx = -1e30f;
  #pragma unroll
  for (int j = 0; j < 16; ++j) {
    float x = maxv[b * HWs + t + j * 256];
    float cc = x * x * x;
    c[j] = cc;
    mn = fminf(mn, cc); mx = fmaxf(mx, cc);
  }
  #pragma unroll
  for (int o = 32; o; o >>= 1) { mn = fminf(mn, __shfl_xor(mn, o)); mx = fmaxf(mx, __shfl_xor(mx, o)); }
  __shared__ float smn[4], smx[4];
  int w = t >> 6;
  if ((t & 63) == 0) { smn[w] = mn; smx[w] = mx; }
  __syncthreads();
  mn = fminf(fminf(smn[0], smn[1]), fminf(smn[2], smn[3]));
  mx = fmaxf(fmaxf(smx[0], smx[1]), fmaxf(smx[2], smx[3]));
  float sc = 1.f / (mx - mn);
  #pragma unroll
  for (int j = 0; j < 16; ++j)
    outm[b * HWs + t + j * 256] = 1.f - (c[j] - mn) * sc;
}

// ---------------- K5: top-81 via MSB radix-select (keys distinct) ----------------
// key = (float_bits << 12) | (4095 - idx)  (42 bits; 6 rounds of 8 bits from bit 47)
__global__ __launch_bounds__(256) void k_topk(const float* __restrict__ maxv,
                                              int* __restrict__ tix) {
  __shared__ unsigned int hist[4][256];
  __shared__ unsigned long long slist[TOPK];
  __shared__ unsigned long long bc_prefix;
  __shared__ int bc_need, scount;
  int b = blockIdx.x, t = threadIdx.x;
  int w = t >> 6;
  unsigned long long key[16];
  #pragma unroll
  for (int j = 0; j < 16; ++j) {
    int idx = t + j * 256;
    unsigned int bits = __float_as_uint(maxv[b * HWs + idx]);   // maxv > 0
    key[j] = ((unsigned long long)bits << 12) | (unsigned)(4095 - idx);
  }
  if (t == 0) { bc_prefix = 0ull; bc_need = TOPK; scount = 0; }
  for (int r = 0; r < 6; ++r) {
    int shift = 40 - 8 * r;
    // clear histograms (1024 words / 256 threads)
    unsigned int* hflat = (unsigned int*)hist;
    hflat[t] = 0; hflat[t + 256] = 0; hflat[t + 512] = 0; hflat[t + 768] = 0;
    __syncthreads();
    unsigned long long prefix = bc_prefix;
    // per-thread bin list with local same-bin merge (bounds LDS atomic serialization)
    int bins[16];
    #pragma unroll
    for (int j = 0; j < 16; ++j)
      bins[j] = ((key[j] >> (shift + 8)) == prefix) ? (int)((key[j] >> shift) & 255) : -1;
    #pragma unroll
    for (int j = 0; j < 16; ++j) {
      if (bins[j] >= 0) {
        int cnt = 1;
        #pragma unroll
        for (int j2 = j + 1; j2 < 16; ++j2)
          if (bins[j2] == bins[j]) { bins[j2] = -1; ++cnt; }
        atomicAdd(&hist[w][bins[j]], (unsigned)cnt);
      }
    }
    __syncthreads();
    if (t < 64) {   // wave 0: descending scan to locate the boundary bin
      int cb[4], s = 0;
      #pragma unroll
      for (int j = 0; j < 4; ++j) {
        int bin = 255 - (t * 4 + j);
        cb[j] = (int)(hist[0][bin] + hist[1][bin] + hist[2][bin] + hist[3][bin]);
        s += cb[j];
      }
      int P = s;
      #pragma unroll
      for (int o = 1; o < 64; o <<= 1) {
        int u = __shfl_up(P, o);
        if (t >= o) P += u;
      }
      int need = bc_need;
      unsigned long long mask = __ballot(P >= need);
      int first = __ffsll((long long)mask) - 1;
      if (t == first) {
        int acc = P - s;   // candidates in strictly higher bins
        #pragma unroll
        for (int j = 0; j < 4; ++j) {
          if (acc + cb[j] >= need) {
            bc_prefix = (prefix << 8) | (unsigned)(255 - (t * 4 + j));
            bc_need = need - acc;
            break;
          }
          acc += cb[j];
        }
      }
    }
    __syncthreads();
  }
  unsigned long long K81 = bc_prefix;   // exact 81st-largest key
  #pragma unroll
  for (int j = 0; j < 16; ++j)
    if (key[j] >= K81) {
      int pos = atomicAdd(&scount, 1);
      slist[pos] = key[j];
    }
  __syncthreads();
  if (t < TOPK) {
    unsigned long long mine = slist[t];
    int rank = 0;
    for (int i = 0; i < TOPK; ++i) rank += (slist[i] > mine) ? 1 : 0;
    tix[b * TOPK + rank] = 4095 - (int)(mine & 0xFFFull);
  }
}

// ---------------- K6: gather ----------------
__global__ __launch_bounds__(128) void k_gather(const unsigned short* __restrict__ pF,
    const int* __restrict__ tix, float* __restrict__ outr) {
  int gB_ = blockIdx.x;
  int k = gB_ % TOPK;
  int bb = gB_ / TOPK;
  int b2 = bb & 7, b = bb >> 3;
  int l = b * HWs + tix[b2 * TOPK + k];
  int lt = l >> 4, mrow = l & 15;
  int t = threadIdx.x;
  int ks = t >> 3, gq = (t >> 1) & 3, j0 = (t & 1) * 4;
  int base = ((lt * 16 + ks) * 64 + gq * 16 + mrow) * 8 + j0;
  const unsigned* src = (const unsigned*)(pF + base);
  unsigned u0 = src[0], u1 = src[1];
  float4 v = {bf2f(u0 & 0xffffu), bf2f(u0 >> 16), bf2f(u1 & 0xffffu), bf2f(u1 >> 16)};
  *(float4*)(outr + (size_t)gB_ * NN + t * 4) = v;
}

extern "C" void kernel_launch(void* const* d_in, const int* in_sizes, int n_in,
                              void* d_out, int out_size, void* d_ws, size_t ws_size,
                              hipStream_t stream) {
  const float* x    = (const float*)d_in[0];
  const float* DR   = (const float*)d_in[1];
  const float* win  = (const float*)d_in[2];
  const float* bin  = (const float*)d_in[3];
  const float* sw   = (const float*)d_in[4];
  const float* sb   = (const float*)d_in[5];
  const float* n1w  = (const float*)d_in[6];
  const float* n1b  = (const float*)d_in[7];
  const float* n2w  = (const float*)d_in[8];
  const float* n2b  = (const float*)d_in[9];
  const float* wout = (const float*)d_in[10];
  const float* bout = (const float*)d_in[11];
  float* out = (float*)d_out;
  float* W = (float*)d_ws;

  // workspace layout (float offsets), ~68.4 MB
  unsigned short* drwF  = (unsigned short*)(W);            // 65536 f
  float* t2   = W + 65536;                                 // 512
  float* rcr  = W + 66048;                                 // 512
  float* rclv = W + 66560;                                 // 32768
  float* maxv = W + 99328;                                 // 32768
  unsigned short* drlnF = (unsigned short*)(W + 132096);   // 65536 f
  unsigned short* WoF   = (unsigned short*)(W + 197632);   // 49152 f
  unsigned short* WinF  = (unsigned short*)(W + 246784);   // 49152 f
  unsigned short* semWF = (unsigned short*)(W + 295936);   // 16384 f
  unsigned short* ApF   = (unsigned short*)(W + 312320);   // 4194304 f
  unsigned short* xaF   = (unsigned short*)(W + 4506624);  // 4194304 f (dead after k_sem)
  unsigned short* pF    = (unsigned short*)(W + 4506624);  // 8388608 f (aliases xaF)
  int*   tix  = (int*)(W + 12895232);                      // 648 ints

  float* out_mask = out;
  float* out_img  = out + 32768;
  float* out_res  = out + 32768 + 12582912;

  k_dr    <<<NN, 64, 0, stream>>>(DR, n2w, n2b, n1w, n1b, drwF, drlnF, t2, rcr);
  k_bprep <<<dim3(8, 3),  256, 0, stream>>>(win,  WinF,  CIN);   // Win  [128,384]
  k_bprep <<<dim3(8, 1),  256, 0, stream>>>(sw,   semWF, DD);    // semW [128,128]
  k_bprep <<<dim3(24, 1), 256, 0, stream>>>(wout, WoF,   DD);    // Wo   [384,128]
  k_convin<<<512,  256, 0, stream>>>(x, WinF, bin, xaF);
  k_sem   <<<512,  256, 0, stream>>>(xaF, semWF, sb, n1w, n1b, ApF, rclv);
  k_scores<<<1024, 256, 0, stream>>>(ApF, drwF, t2, rcr, rclv, pF, maxv);
  k_deg   <<<512,  256, 0, stream>>>(pF, drlnF, WoF, bout, out_img);
  k_mask  <<<BB,   256, 0, stream>>>(maxv, out_mask);
  k_topk  <<<BB,   256, 0, stream>>>(maxv, tix);
  k_gather<<<BB * BB * TOPK, 128, 0, stream>>>(pF, tix, out_res);
}